// Round 6
// baseline (239.268 us; speedup 1.0000x reference)
//
#include <hip/hip_runtime.h>

#define B_ 2
#define N_ 2048
#define H_ 8
#define DH_ 32
#define E_ 65536
#define DIN_ 256
#define KT 256
#define NKT (N_ / KT)
#define ECAP 32
#define QSCALE 0.2550348872f           // log2(e)/sqrt(DH)
#define LOG2E 1.4426950408889634f
#define LOG2MIN -19.931568569324174f   // log2(1e-6)

typedef short bf16x8 __attribute__((ext_vector_type(8)));
typedef float floatx4 __attribute__((ext_vector_type(4)));

__device__ __forceinline__ unsigned short f2b(float f){
  union { float f; unsigned int u; } v; v.f = f;
  return (unsigned short)((v.u + 0x7fffu + ((v.u >> 16) & 1u)) >> 16);
}
__device__ __forceinline__ bf16x8 f8_to_bf(const float* p){
  float4 a = *(const float4*)p, b = *(const float4*)(p + 4);
  bf16x8 r;
  r[0] = (short)f2b(a.x); r[1] = (short)f2b(a.y); r[2] = (short)f2b(a.z); r[3] = (short)f2b(a.w);
  r[4] = (short)f2b(b.x); r[5] = (short)f2b(b.y); r[6] = (short)f2b(b.z); r[7] = (short)f2b(b.w);
  return r;
}
__device__ __forceinline__ unsigned int cvt_pk_bf16(float lo, float hi){
  unsigned int r;
  asm("v_cvt_pk_bf16_f32 %0, %1, %2" : "=v"(r) : "v"(lo), "v"(hi));
  return r;
}
__device__ __forceinline__ float fexp2(float x){
  float r;
  asm("v_exp_f32 %0, %1" : "=v"(r) : "v"(x));
  return r;
}

// ---------------- prep: ffn (blocks 0..511) + fill (512..1023) + wT (1024..1279) ----------------
__global__ __launch_bounds__(256) void prep_kernel(
    const float* __restrict__ eattr,
    const float* __restrict__ w1, const float* __restrict__ b1,
    const float* __restrict__ w2, const float* __restrict__ b2,
    float* __restrict__ ea,
    const int* __restrict__ ei, int* __restrict__ cnt, unsigned int* __restrict__ pck,
    const float* __restrict__ w, unsigned short* __restrict__ wT)
{
  int bb = blockIdx.x, tid = threadIdx.x;
  if (bb < 512){
    __shared__ float W1[64], W2[64], Bv1[8], Bv2[8];
    if (tid < 64){ W1[tid] = w1[tid]; W2[tid] = w2[tid]; }
    if (tid < 8){ Bv1[tid] = b1[tid]; Bv2[tid] = b2[tid]; }
    __syncthreads();
    int gid = bb * 256 + tid;                 // b*E + e
    const float* ep = eattr + (size_t)gid * 8;
    float cur[8];
#pragma unroll
    for (int i = 0; i < 8; ++i) cur[i] = ep[i];
#pragma unroll
    for (int pass = 0; pass < 2; ++pass){
      float t[8];
#pragma unroll
      for (int j = 0; j < 8; ++j){
        float s = Bv1[j];
#pragma unroll
        for (int i = 0; i < 8; ++i) s += cur[i] * W1[i * 8 + j];
        t[j] = fmaxf(s, 0.f);
      }
#pragma unroll
      for (int j = 0; j < 8; ++j){
        float s = Bv2[j];
#pragma unroll
        for (int i = 0; i < 8; ++i) s += t[i] * W2[i * 8 + j];
        cur[j] = s;
      }
    }
    float* op = ea + (size_t)gid * 8;
#pragma unroll
    for (int j = 0; j < 8; ++j) op[j] = cur[j] * LOG2E;   // exp2-domain
  } else if (bb < 1024){
    int gid = (bb - 512) * 256 + tid;         // 0..131071
    int b = gid >> 16, e = gid & (E_ - 1);
    int u = ei[(size_t)b * 2 * E_ + e];
    int v = ei[(size_t)b * 2 * E_ + E_ + e];
    int bucket = ((b << 11) + u) * 8 + (v >> 8);
    int slot = atomicAdd(&cnt[bucket], 1);
    if (slot < ECAP) pck[(size_t)bucket * ECAP + slot] = ((unsigned int)e << 11) | (unsigned int)v;
  } else {
    int k = bb - 1024;                        // 0..255
    for (int c = tid; c < 768; c += 256)
      wT[(size_t)c * 256 + k] = f2b(w[(size_t)k * 768 + c]);
  }
}

// ---------------- QKV projection: (4096x256)@(256x768), MFMA; Q pre-scaled by log2e/sqrt(DH) ----------------
__global__ __launch_bounds__(256) void qkv_kernel(
    const float* __restrict__ x, const unsigned short* __restrict__ wT,
    const float* __restrict__ bias,
    unsigned short* __restrict__ Qb, unsigned short* __restrict__ Kb, unsigned short* __restrict__ Vt)
{
  int tid = threadIdx.x;
  int wave = tid >> 6, lane = tid & 63, m = lane & 15, quad = lane >> 4;
  int rowbase = blockIdx.x * 16;
  int colbase = blockIdx.y * 64 + wave * 16;
  floatx4 acc = {0.f, 0.f, 0.f, 0.f};
#pragma unroll
  for (int kb = 0; kb < 8; ++kb){
    bf16x8 af = f8_to_bf(x + (size_t)(rowbase + m) * DIN_ + kb * 32 + quad * 8);
    bf16x8 bf = *(const bf16x8*)(wT + (size_t)(colbase + m) * DIN_ + kb * 32 + quad * 8);
    acc = __builtin_amdgcn_mfma_f32_16x16x32_bf16(af, bf, acc, 0, 0, 0);
  }
  int ccol = colbase + m;
  int which = ccol >> 8, hh = (ccol >> 5) & 7, dh = ccol & 31;
  float bv = bias[ccol];
  int row0 = rowbase + quad * 4;
  int bidx = row0 >> 11, n0 = row0 & (N_ - 1);
  size_t bh = (size_t)(bidx * H_ + hh);
  if (which == 0){
#pragma unroll
    for (int r = 0; r < 4; ++r)
      Qb[(bh * N_ + n0 + r) * DH_ + dh] = f2b((acc[r] + bv) * QSCALE);
  } else if (which == 1){
#pragma unroll
    for (int r = 0; r < 4; ++r)
      Kb[(bh * N_ + n0 + r) * DH_ + dh] = f2b(acc[r] + bv);
  } else {
    ushort4 st;
    st.x = f2b(acc[0] + bv); st.y = f2b(acc[1] + bv);
    st.z = f2b(acc[2] + bv); st.w = f2b(acc[3] + bv);
    *(ushort4*)(Vt + (bh * DH_ + dh) * N_ + n0) = st;
  }
}

// ---------------- fused flash attention: TWO independent q-tiles per WG (2-chain ILP) ----------------
// Round-4 numerics (online max) duplicated for chains A (q rows qp*32..+15) and B (+16..+31).
// K/V fragments are loaded once and feed both chains; the two chains are independent,
// giving the scheduler 2x ILP on the latency-bound critical path. Grid 1024 = one residency
// round at 4 WGs/CU (LDS 35.8 KB). Fence-free wave-private LDS, scatter pipelined 1 tile ahead.
__global__ __launch_bounds__(256, 4) void attn_kernel(
    const unsigned short* __restrict__ Qb, const unsigned short* __restrict__ Kb,
    const unsigned short* __restrict__ Vt, const float* __restrict__ adj,
    const float* __restrict__ ea, const int* __restrict__ cnt, const unsigned int* __restrict__ pck,
    const float* __restrict__ shifts, const float* __restrict__ widths,
    const float* __restrict__ selfW, float* __restrict__ out)
{
  __shared__ float S2[2][4][16][68];      // per-chain, wave-private 16x64 (+4 pad)
  __shared__ float mfin[2][4][16], lfin[2][4][16];

  int bid = blockIdx.x;                   // 0..1023
  // head-affinity XCD swizzle (bijective): XCD = bid&7; h fastest in time within an XCD
  int xcd = bid & 7, idx = bid >> 3;      // idx 0..127
  int h = idx & 7;
  int bqp = xcd * 16 + (idx >> 3);        // 0..127 = b*64 + qp
  int b = bqp >> 6, qp = bqp & 63;
  int qbaseA = qp * 32, qbaseB = qbaseA + 16;
  int tid = threadIdx.x, wave = tid >> 6, lane = tid & 63, m = lane & 15, quad = lane >> 4;
  float shift_h = shifts[h];
  float w_h = widths[h];
  float i2w_h = LOG2E / (2.f * w_h * w_h);
  float selfW_h = selfW[h] * LOG2E;
  size_t krow = (size_t)(b * H_ + h) * N_;
  size_t vrow = (size_t)(b * H_ + h) * DH_;
  bf16x8 qfragA = *(const bf16x8*)(Qb + (krow + qbaseA + m) * DH_ + quad * 8);
  bf16x8 qfragB = *(const bf16x8*)(Qb + (krow + qbaseB + m) * DH_ + quad * 8);
  float (*SwA)[68] = S2[0][wave];
  float (*SwB)[68] = S2[1][wave];
  int wcol = wave * 64;

  int rr = lane >> 2, sl0 = lane & 3;     // scatter: 4 lanes per row
  const int* cntpA = cnt + ((size_t)(b * N_) + qbaseA + rr) * 8;
  const int* cntpB = cntpA + 128;         // +16 rows * 8
  const unsigned int* pckpA = pck + ((size_t)((b * N_ + qbaseA + rr) * 8)) * ECAP;
  const unsigned int* pckpB = pckpA + 128 * ECAP;
  const float* eabase = ea + (size_t)b * E_ * H_ + h;
  const float* adjpA = adj + ((size_t)b * N_ + qbaseA + m) * N_ + wcol + quad * 8;
  const float* adjpB = adjpA + (size_t)16 * N_;
  const unsigned short* vp0 = Vt + (vrow + m) * N_ + wcol + quad * 8;
  const unsigned short* vp1 = Vt + (vrow + 16 + m) * N_ + wcol + quad * 8;
  const unsigned short* kp  = Kb + (krow + wcol + m) * DH_ + quad * 8;

  floatx4 sh4 = {shift_h, shift_h, shift_h, shift_h};
  floatx4 ni4 = {-i2w_h, -i2w_h, -i2w_h, -i2w_h};
  floatx4 lm4 = {LOG2MIN, LOG2MIN, LOG2MIN, LOG2MIN};
  floatx4 z4  = {0.f, 0.f, 0.f, 0.f};

  float mcurA = -1e30f, lcurA = 0.f;
  float mcurB = -1e30f, lcurB = 0.f;
  floatx4 oA0 = z4, oA1 = z4, oB0 = z4, oB1 = z4;

  // ---- scatter pipeline prologue (tile 0), chains A and B ----
  int nbA = cntpA[0]; nbA = nbA > ECAP ? ECAP : nbA;
  int nbB = cntpB[0]; nbB = nbB > ECAP ? ECAP : nbB;
  unsigned int pA0 = pckpA[sl0], pA1 = pckpA[sl0 + 4];
  unsigned int pB0 = pckpB[sl0], pB1 = pckpB[sl0 + 4];
  int cA0 = (int)(pA0 & (N_ - 1)) - wcol, cA1 = (int)(pA1 & (N_ - 1)) - wcol;
  int cB0 = (int)(pB0 & (N_ - 1)) - wcol, cB1 = (int)(pB1 & (N_ - 1)) - wcol;
  bool gA0 = (sl0 < nbA) && ((unsigned)cA0 < 64u);
  bool gA1 = (sl0 + 4 < nbA) && ((unsigned)cA1 < 64u);
  bool gB0 = (sl0 < nbB) && ((unsigned)cB0 < 64u);
  bool gB1 = (sl0 + 4 < nbB) && ((unsigned)cB1 < 64u);
  float eA0 = 0.f, eA1 = 0.f, eB0 = 0.f, eB1 = 0.f;
  if (gA0) eA0 = eabase[(size_t)(pA0 >> 11) * H_];
  if (gA1) eA1 = eabase[(size_t)(pA1 >> 11) * H_];
  if (gB0) eB0 = eabase[(size_t)(pB0 >> 11) * H_];
  if (gB1) eB1 = eabase[(size_t)(pB1 >> 11) * H_];

#pragma unroll
  for (int kt = 0; kt < NKT; ++kt){
    int k0 = kt * KT;
    // ---- prefetch next-tile scatter metadata (both chains) ----
    int nbA_n = 0, nbB_n = 0;
    unsigned int pA0_n = 0, pA1_n = 0, pB0_n = 0, pB1_n = 0;
    if (kt + 1 < NKT){
      nbA_n = cntpA[kt + 1];            nbB_n = cntpB[kt + 1];
      pA0_n = pckpA[(kt + 1) * ECAP + sl0];  pA1_n = pckpA[(kt + 1) * ECAP + sl0 + 4];
      pB0_n = pckpB[(kt + 1) * ECAP + sl0];  pB1_n = pckpB[(kt + 1) * ECAP + sl0 + 4];
    }
    // ---- adj loads (both chains; consumed by moire) ----
    const float* apA = adjpA + k0;
    const float* apB = adjpB + k0;
    floatx4 aA00 = *(const floatx4*)(apA);      floatx4 aA01 = *(const floatx4*)(apA + 4);
    floatx4 aA10 = *(const floatx4*)(apA + 32); floatx4 aA11 = *(const floatx4*)(apA + 36);
    floatx4 aB00 = *(const floatx4*)(apB);      floatx4 aB01 = *(const floatx4*)(apB + 4);
    floatx4 aB10 = *(const floatx4*)(apB + 32); floatx4 aB11 = *(const floatx4*)(apB + 36);

    // ---- QK^T: shared K fragment feeds both chains ----
#pragma unroll
    for (int s = 0; s < 4; ++s){
      bf16x8 kf = *(const bf16x8*)(kp + (size_t)(k0 + s * 16) * DH_);
      floatx4 accA = __builtin_amdgcn_mfma_f32_16x16x32_bf16(qfragA, kf, z4, 0, 0, 0);
      floatx4 accB = __builtin_amdgcn_mfma_f32_16x16x32_bf16(qfragB, kf, z4, 0, 0, 0);
#pragma unroll
      for (int r = 0; r < 4; ++r){
        SwA[quad * 4 + r][s * 16 + m] = accA[r];
        SwB[quad * 4 + r][s * 16 + m] = accB[r];
      }
    }
    // ---- diagonal self-loop fixups ----
    {
      int dwA = qbaseA - k0 - wcol;
      if ((unsigned)dwA < 64u && lane < 16) SwA[lane][dwA + lane] += selfW_h;
      int dwB = qbaseB - k0 - wcol;
      if ((unsigned)dwB < 64u && lane < 16) SwB[lane][dwB + lane] += selfW_h;
    }
    // ---- scatter apply (preloaded one tile ago) ----
    if (gA0) SwA[rr][cA0] += eA0;
    if (gA1) SwA[rr][cA1] += eA1;
    if (gB0) SwB[rr][cB0] += eB0;
    if (gB1) SwB[rr][cB1] += eB1;
    if (nbA > 8){
      for (int slot = sl0 + 8; slot < nbA; slot += 4){
        unsigned int p = pckpA[kt * ECAP + slot];
        int c = (int)(p & (N_ - 1)) - k0 - wcol;
        if ((unsigned)c < 64u) SwA[rr][c] += eabase[(size_t)(p >> 11) * H_];
      }
    }
    if (nbB > 8){
      for (int slot = sl0 + 8; slot < nbB; slot += 4){
        unsigned int p = pckpB[kt * ECAP + slot];
        int c = (int)(p & (N_ - 1)) - k0 - wcol;
        if ((unsigned)c < 64u) SwB[rr][c] += eabase[(size_t)(p >> 11) * H_];
      }
    }
    // ---- issue guarded ea loads for next tile ----
    int cA0_n = 0, cA1_n = 0, cB0_n = 0, cB1_n = 0;
    bool gA0_n = false, gA1_n = false, gB0_n = false, gB1_n = false;
    float eA0_n = 0.f, eA1_n = 0.f, eB0_n = 0.f, eB1_n = 0.f;
    if (kt + 1 < NKT){
      nbA_n = nbA_n > ECAP ? ECAP : nbA_n;
      nbB_n = nbB_n > ECAP ? ECAP : nbB_n;
      cA0_n = (int)(pA0_n & (N_ - 1)) - (k0 + KT) - wcol;
      cA1_n = (int)(pA1_n & (N_ - 1)) - (k0 + KT) - wcol;
      cB0_n = (int)(pB0_n & (N_ - 1)) - (k0 + KT) - wcol;
      cB1_n = (int)(pB1_n & (N_ - 1)) - (k0 + KT) - wcol;
      gA0_n = (sl0 < nbA_n) && ((unsigned)cA0_n < 64u);
      gA1_n = (sl0 + 4 < nbA_n) && ((unsigned)cA1_n < 64u);
      gB0_n = (sl0 < nbB_n) && ((unsigned)cB0_n < 64u);
      gB1_n = (sl0 + 4 < nbB_n) && ((unsigned)cB1_n < 64u);
      if (gA0_n) eA0_n = eabase[(size_t)(pA0_n >> 11) * H_];
      if (gA1_n) eA1_n = eabase[(size_t)(pA1_n >> 11) * H_];
      if (gB0_n) eB0_n = eabase[(size_t)(pB0_n >> 11) * H_];
      if (gB1_n) eB1_n = eabase[(size_t)(pB1_n >> 11) * H_];
    }
    // ---- V loads (shared by both chains) ----
    bf16x8 vf00 = *(const bf16x8*)(vp0 + k0);
    bf16x8 vf01 = *(const bf16x8*)(vp1 + k0);
    bf16x8 vf10 = *(const bf16x8*)(vp0 + k0 + 32);
    bf16x8 vf11 = *(const bf16x8*)(vp1 + k0 + 32);

    // ================= chain A softmax + PV =================
    {
      const float* sp = &SwA[m][quad * 8];
      floatx4 s00 = *(const floatx4*)(sp);
      floatx4 s01 = *(const floatx4*)(sp + 4);
      floatx4 s10 = *(const floatx4*)(sp + 32);
      floatx4 s11 = *(const floatx4*)(sp + 36);
      floatx4 d;
      d = aA00 - sh4; s00 += __builtin_elementwise_max(d * d * ni4, lm4);
      d = aA01 - sh4; s01 += __builtin_elementwise_max(d * d * ni4, lm4);
      d = aA10 - sh4; s10 += __builtin_elementwise_max(d * d * ni4, lm4);
      d = aA11 - sh4; s11 += __builtin_elementwise_max(d * d * ni4, lm4);
      float lm = fmaxf(fmaxf(fmaxf(s00.x, s00.y), fmaxf(s00.z, s00.w)),
                       fmaxf(fmaxf(s01.x, s01.y), fmaxf(s01.z, s01.w)));
      lm = fmaxf(lm, fmaxf(fmaxf(fmaxf(s10.x, s10.y), fmaxf(s10.z, s10.w)),
                           fmaxf(fmaxf(s11.x, s11.y), fmaxf(s11.z, s11.w))));
      lm = fmaxf(lm, __shfl_xor(lm, 16));
      lm = fmaxf(lm, __shfl_xor(lm, 32));
      float mnew = fmaxf(mcurA, lm);
      float al = fexp2(mcurA - mnew);
      mcurA = mnew;
      float al0 = __shfl(al, quad * 4 + 0);
      float al1 = __shfl(al, quad * 4 + 1);
      float al2 = __shfl(al, quad * 4 + 2);
      float al3 = __shfl(al, quad * 4 + 3);
      oA0[0] *= al0; oA0[1] *= al1; oA0[2] *= al2; oA0[3] *= al3;
      oA1[0] *= al0; oA1[1] *= al1; oA1[2] *= al2; oA1[3] *= al3;
      floatx4 m4 = {mcurA, mcurA, mcurA, mcurA};
      floatx4 e0v = s00 - m4, e1v = s01 - m4, e2v = s10 - m4, e3v = s11 - m4;
      float ps = 0.f, p0, p1;
      union { bf16x8 v; unsigned int u[4]; } P;
      p0 = fexp2(e0v.x); p1 = fexp2(e0v.y); ps += p0 + p1; P.u[0] = cvt_pk_bf16(p0, p1);
      p0 = fexp2(e0v.z); p1 = fexp2(e0v.w); ps += p0 + p1; P.u[1] = cvt_pk_bf16(p0, p1);
      p0 = fexp2(e1v.x); p1 = fexp2(e1v.y); ps += p0 + p1; P.u[2] = cvt_pk_bf16(p0, p1);
      p0 = fexp2(e1v.z); p1 = fexp2(e1v.w); ps += p0 + p1; P.u[3] = cvt_pk_bf16(p0, p1);
      oA0 = __builtin_amdgcn_mfma_f32_16x16x32_bf16(P.v, vf00, oA0, 0, 0, 0);
      oA1 = __builtin_amdgcn_mfma_f32_16x16x32_bf16(P.v, vf01, oA1, 0, 0, 0);
      p0 = fexp2(e2v.x); p1 = fexp2(e2v.y); ps += p0 + p1; P.u[0] = cvt_pk_bf16(p0, p1);
      p0 = fexp2(e2v.z); p1 = fexp2(e2v.w); ps += p0 + p1; P.u[1] = cvt_pk_bf16(p0, p1);
      p0 = fexp2(e3v.x); p1 = fexp2(e3v.y); ps += p0 + p1; P.u[2] = cvt_pk_bf16(p0, p1);
      p0 = fexp2(e3v.z); p1 = fexp2(e3v.w); ps += p0 + p1; P.u[3] = cvt_pk_bf16(p0, p1);
      oA0 = __builtin_amdgcn_mfma_f32_16x16x32_bf16(P.v, vf10, oA0, 0, 0, 0);
      oA1 = __builtin_amdgcn_mfma_f32_16x16x32_bf16(P.v, vf11, oA1, 0, 0, 0);
      ps += __shfl_xor(ps, 16);
      ps += __shfl_xor(ps, 32);
      lcurA = lcurA * al + ps;
    }
    // ================= chain B softmax + PV =================
    {
      const float* sp = &SwB[m][quad * 8];
      floatx4 s00 = *(const floatx4*)(sp);
      floatx4 s01 = *(const floatx4*)(sp + 4);
      floatx4 s10 = *(const floatx4*)(sp + 32);
      floatx4 s11 = *(const floatx4*)(sp + 36);
      floatx4 d;
      d = aB00 - sh4; s00 += __builtin_elementwise_max(d * d * ni4, lm4);
      d = aB01 - sh4; s01 += __builtin_elementwise_max(d * d * ni4, lm4);
      d = aB10 - sh4; s10 += __builtin_elementwise_max(d * d * ni4, lm4);
      d = aB11 - sh4; s11 += __builtin_elementwise_max(d * d * ni4, lm4);
      float lm = fmaxf(fmaxf(fmaxf(s00.x, s00.y), fmaxf(s00.z, s00.w)),
                       fmaxf(fmaxf(s01.x, s01.y), fmaxf(s01.z, s01.w)));
      lm = fmaxf(lm, fmaxf(fmaxf(fmaxf(s10.x, s10.y), fmaxf(s10.z, s10.w)),
                           fmaxf(fmaxf(s11.x, s11.y), fmaxf(s11.z, s11.w))));
      lm = fmaxf(lm, __shfl_xor(lm, 16));
      lm = fmaxf(lm, __shfl_xor(lm, 32));
      float mnew = fmaxf(mcurB, lm);
      float al = fexp2(mcurB - mnew);
      mcurB = mnew;
      float al0 = __shfl(al, quad * 4 + 0);
      float al1 = __shfl(al, quad * 4 + 1);
      float al2 = __shfl(al, quad * 4 + 2);
      float al3 = __shfl(al, quad * 4 + 3);
      oB0[0] *= al0; oB0[1] *= al1; oB0[2] *= al2; oB0[3] *= al3;
      oB1[0] *= al0; oB1[1] *= al1; oB1[2] *= al2; oB1[3] *= al3;
      floatx4 m4 = {mcurB, mcurB, mcurB, mcurB};
      floatx4 e0v = s00 - m4, e1v = s01 - m4, e2v = s10 - m4, e3v = s11 - m4;
      float ps = 0.f, p0, p1;
      union { bf16x8 v; unsigned int u[4]; } P;
      p0 = fexp2(e0v.x); p1 = fexp2(e0v.y); ps += p0 + p1; P.u[0] = cvt_pk_bf16(p0, p1);
      p0 = fexp2(e0v.z); p1 = fexp2(e0v.w); ps += p0 + p1; P.u[1] = cvt_pk_bf16(p0, p1);
      p0 = fexp2(e1v.x); p1 = fexp2(e1v.y); ps += p0 + p1; P.u[2] = cvt_pk_bf16(p0, p1);
      p0 = fexp2(e1v.z); p1 = fexp2(e1v.w); ps += p0 + p1; P.u[3] = cvt_pk_bf16(p0, p1);
      oB0 = __builtin_amdgcn_mfma_f32_16x16x32_bf16(P.v, vf00, oB0, 0, 0, 0);
      oB1 = __builtin_amdgcn_mfma_f32_16x16x32_bf16(P.v, vf01, oB1, 0, 0, 0);
      p0 = fexp2(e2v.x); p1 = fexp2(e2v.y); ps += p0 + p1; P.u[0] = cvt_pk_bf16(p0, p1);
      p0 = fexp2(e2v.z); p1 = fexp2(e2v.w); ps += p0 + p1; P.u[1] = cvt_pk_bf16(p0, p1);
      p0 = fexp2(e3v.x); p1 = fexp2(e3v.y); ps += p0 + p1; P.u[2] = cvt_pk_bf16(p0, p1);
      p0 = fexp2(e3v.z); p1 = fexp2(e3v.w); ps += p0 + p1; P.u[3] = cvt_pk_bf16(p0, p1);
      oB0 = __builtin_amdgcn_mfma_f32_16x16x32_bf16(P.v, vf10, oB0, 0, 0, 0);
      oB1 = __builtin_amdgcn_mfma_f32_16x16x32_bf16(P.v, vf11, oB1, 0, 0, 0);
      ps += __shfl_xor(ps, 16);
      ps += __shfl_xor(ps, 32);
      lcurB = lcurB * al + ps;
    }
    // ---- rotate scatter pipelines ----
    nbA = nbA_n; gA0 = gA0_n; gA1 = gA1_n; cA0 = cA0_n; cA1 = cA1_n; eA0 = eA0_n; eA1 = eA1_n;
    nbB = nbB_n; gB0 = gB0_n; gB1 = gB1_n; cB0 = cB0_n; cB1 = cB1_n; eB0 = eB0_n; eB1 = eB1_n;
  }

  // ---- cross-wave merge, both chains ----
  if (quad == 0){
    mfin[0][wave][m] = mcurA; lfin[0][wave][m] = lcurA;
    mfin[1][wave][m] = mcurB; lfin[1][wave][m] = lcurB;
  }
  float* OwA = &S2[0][wave][0][0];
  float* OwB = &S2[1][wave][0][0];
#pragma unroll
  for (int r = 0; r < 4; ++r){
    OwA[(quad * 4 + r) * 32 + m]      = oA0[r];
    OwA[(quad * 4 + r) * 32 + 16 + m] = oA1[r];
    OwB[(quad * 4 + r) * 32 + m]      = oB0[r];
    OwB[(quad * 4 + r) * 32 + 16 + m] = oB1[r];
  }
  __syncthreads();
#pragma unroll
  for (int ii = 0; ii < 4; ++ii){
    int i = tid + ii * 256;               // 0..1023
    int chain = i >> 9, r = (i >> 5) & 15, dcol = i & 31;
    const float* Sv = &S2[chain][0][0][0];
    float m0 = mfin[chain][0][r], m1 = mfin[chain][1][r];
    float m2 = mfin[chain][2][r], m3 = mfin[chain][3][r];
    float mg = fmaxf(fmaxf(m0, m1), fmaxf(m2, m3));
    float w0 = fexp2(m0 - mg), w1 = fexp2(m1 - mg);
    float w2 = fexp2(m2 - mg), w3 = fexp2(m3 - mg);
    int o_idx = r * 32 + dcol;
    float o = Sv[o_idx] * w0 + Sv[1088 + o_idx] * w1
            + Sv[2176 + o_idx] * w2 + Sv[3264 + o_idx] * w3;
    float l = lfin[chain][0][r] * w0 + lfin[chain][1][r] * w1
            + lfin[chain][2][r] * w2 + lfin[chain][3][r] * w3;
    int qb = chain ? qbaseB : qbaseA;
    out[((size_t)b * N_ + qb + r) * (H_ * DH_) + h * DH_ + dcol] = o / l;
  }
}

extern "C" void kernel_launch(void* const* d_in, const int* in_sizes, int n_in,
                              void* d_out, int out_size, void* d_ws, size_t ws_size,
                              hipStream_t stream)
{
  const float* x      = (const float*)d_in[0];
  const float* adj    = (const float*)d_in[1];
  const float* eattr  = (const float*)d_in[2];
  const float* qkvw   = (const float*)d_in[3];
  const float* qkvb   = (const float*)d_in[4];
  const float* ew1    = (const float*)d_in[5];
  const float* eb1    = (const float*)d_in[6];
  const float* ew2    = (const float*)d_in[7];
  const float* eb2    = (const float*)d_in[8];
  const float* shifts = (const float*)d_in[9];
  const float* widths = (const float*)d_in[10];
  const float* selfW  = (const float*)d_in[11];
  const int*   ei     = (const int*)d_in[12];
  float* out = (float*)d_out;

  char* ws = (char*)d_ws;
  unsigned short* Qb  = (unsigned short*)(ws);                        // 2 MB
  unsigned short* Kb  = (unsigned short*)(ws + ((size_t)2 << 20));    // 2 MB
  unsigned short* Vt  = (unsigned short*)(ws + ((size_t)4 << 20));    // 2 MB
  unsigned short* wT  = (unsigned short*)(ws + ((size_t)6 << 20));    // 384 KB
  float*          ea  = (float*)(ws + ((size_t)7 << 20));             // 4 MB
  int*            cnt = (int*)(ws + ((size_t)11 << 20));              // 128 KB
  unsigned int*  pck  = (unsigned int*)(ws + ((size_t)12 << 20));     // 4 MB (total 16 MB)

  hipMemsetAsync(cnt, 0, (size_t)B_ * N_ * 8 * sizeof(int), stream);
  hipLaunchKernelGGL(prep_kernel, dim3(1280), dim3(256), 0, stream,
                     eattr, ew1, eb1, ew2, eb2, ea, ei, cnt, pck, qkvw, wT);
  hipLaunchKernelGGL(qkv_kernel, dim3(256, 12), dim3(256), 0, stream, x, wT, qkvb, Qb, Kb, Vt);
  hipLaunchKernelGGL(attn_kernel, dim3(B_ * H_ * (N_ / 32)), dim3(256), 0, stream,
                     Qb, Kb, Vt, adj, ea, cnt, pck, shifts, widths, selfW, out);
}

// Round 7
// 238.480 us; speedup vs baseline: 1.0033x; 1.0033x over previous
//
#include <hip/hip_runtime.h>

#define B_ 2
#define N_ 2048
#define H_ 8
#define DH_ 32
#define E_ 65536
#define DIN_ 256
#define KT 256
#define NKT (N_ / KT)
#define ECAP 32
#define QSCALE 0.2550348872f           // log2(e)/sqrt(DH)
#define LOG2E 1.4426950408889634f
#define LOG2MIN -19.931568569324174f   // log2(1e-6)

typedef short bf16x8 __attribute__((ext_vector_type(8)));
typedef float floatx4 __attribute__((ext_vector_type(4)));

__device__ __forceinline__ unsigned short f2b(float f){
  union { float f; unsigned int u; } v; v.f = f;
  return (unsigned short)((v.u + 0x7fffu + ((v.u >> 16) & 1u)) >> 16);
}
__device__ __forceinline__ bf16x8 f8_to_bf(const float* p){
  float4 a = *(const float4*)p, b = *(const float4*)(p + 4);
  bf16x8 r;
  r[0] = (short)f2b(a.x); r[1] = (short)f2b(a.y); r[2] = (short)f2b(a.z); r[3] = (short)f2b(a.w);
  r[4] = (short)f2b(b.x); r[5] = (short)f2b(b.y); r[6] = (short)f2b(b.z); r[7] = (short)f2b(b.w);
  return r;
}
__device__ __forceinline__ unsigned int cvt_pk_bf16(float lo, float hi){
  unsigned int r;
  asm("v_cvt_pk_bf16_f32 %0, %1, %2" : "=v"(r) : "v"(lo), "v"(hi));
  return r;
}
__device__ __forceinline__ float fexp2(float x){
  float r;
  asm("v_exp_f32 %0, %1" : "=v"(r) : "v"(x));
  return r;
}

// ---------------- prep: ffn (blocks 0..511) + fill (512..1023) + wT (1024..1279) ----------------
__global__ __launch_bounds__(256) void prep_kernel(
    const float* __restrict__ eattr,
    const float* __restrict__ w1, const float* __restrict__ b1,
    const float* __restrict__ w2, const float* __restrict__ b2,
    float* __restrict__ ea,
    const int* __restrict__ ei, int* __restrict__ cnt, unsigned int* __restrict__ pck,
    const float* __restrict__ w, unsigned short* __restrict__ wT)
{
  int bb = blockIdx.x, tid = threadIdx.x;
  if (bb < 512){
    __shared__ float W1[64], W2[64], Bv1[8], Bv2[8];
    if (tid < 64){ W1[tid] = w1[tid]; W2[tid] = w2[tid]; }
    if (tid < 8){ Bv1[tid] = b1[tid]; Bv2[tid] = b2[tid]; }
    __syncthreads();
    int gid = bb * 256 + tid;                 // b*E + e
    const float* ep = eattr + (size_t)gid * 8;
    float cur[8];
#pragma unroll
    for (int i = 0; i < 8; ++i) cur[i] = ep[i];
#pragma unroll
    for (int pass = 0; pass < 2; ++pass){
      float t[8];
#pragma unroll
      for (int j = 0; j < 8; ++j){
        float s = Bv1[j];
#pragma unroll
        for (int i = 0; i < 8; ++i) s += cur[i] * W1[i * 8 + j];
        t[j] = fmaxf(s, 0.f);
      }
#pragma unroll
      for (int j = 0; j < 8; ++j){
        float s = Bv2[j];
#pragma unroll
        for (int i = 0; i < 8; ++i) s += t[i] * W2[i * 8 + j];
        cur[j] = s;
      }
    }
    float* op = ea + (size_t)gid * 8;
#pragma unroll
    for (int j = 0; j < 8; ++j) op[j] = cur[j] * LOG2E;   // exp2-domain
  } else if (bb < 1024){
    int gid = (bb - 512) * 256 + tid;         // 0..131071
    int b = gid >> 16, e = gid & (E_ - 1);
    int u = ei[(size_t)b * 2 * E_ + e];
    int v = ei[(size_t)b * 2 * E_ + E_ + e];
    int bucket = ((b << 11) + u) * 8 + (v >> 8);
    int slot = atomicAdd(&cnt[bucket], 1);
    if (slot < ECAP) pck[(size_t)bucket * ECAP + slot] = ((unsigned int)e << 11) | (unsigned int)v;
  } else {
    int k = bb - 1024;                        // 0..255
    for (int c = tid; c < 768; c += 256)
      wT[(size_t)c * 256 + k] = f2b(w[(size_t)k * 768 + c]);
  }
}

// ---------------- QKV projection: (4096x256)@(256x768), MFMA; Q pre-scaled by log2e/sqrt(DH) ----------------
__global__ __launch_bounds__(256) void qkv_kernel(
    const float* __restrict__ x, const unsigned short* __restrict__ wT,
    const float* __restrict__ bias,
    unsigned short* __restrict__ Qb, unsigned short* __restrict__ Kb, unsigned short* __restrict__ Vt)
{
  int tid = threadIdx.x;
  int wave = tid >> 6, lane = tid & 63, m = lane & 15, quad = lane >> 4;
  int rowbase = blockIdx.x * 16;
  int colbase = blockIdx.y * 64 + wave * 16;
  floatx4 acc = {0.f, 0.f, 0.f, 0.f};
#pragma unroll
  for (int kb = 0; kb < 8; ++kb){
    bf16x8 af = f8_to_bf(x + (size_t)(rowbase + m) * DIN_ + kb * 32 + quad * 8);
    bf16x8 bf = *(const bf16x8*)(wT + (size_t)(colbase + m) * DIN_ + kb * 32 + quad * 8);
    acc = __builtin_amdgcn_mfma_f32_16x16x32_bf16(af, bf, acc, 0, 0, 0);
  }
  int ccol = colbase + m;
  int which = ccol >> 8, hh = (ccol >> 5) & 7, dh = ccol & 31;
  float bv = bias[ccol];
  int row0 = rowbase + quad * 4;
  int bidx = row0 >> 11, n0 = row0 & (N_ - 1);
  size_t bh = (size_t)(bidx * H_ + hh);
  if (which == 0){
#pragma unroll
    for (int r = 0; r < 4; ++r)
      Qb[(bh * N_ + n0 + r) * DH_ + dh] = f2b((acc[r] + bv) * QSCALE);
  } else if (which == 1){
#pragma unroll
    for (int r = 0; r < 4; ++r)
      Kb[(bh * N_ + n0 + r) * DH_ + dh] = f2b(acc[r] + bv);
  } else {
    ushort4 st;
    st.x = f2b(acc[0] + bv); st.y = f2b(acc[1] + bv);
    st.z = f2b(acc[2] + bv); st.w = f2b(acc[3] + bv);
    *(ushort4*)(Vt + (bh * DH_ + dh) * N_ + n0) = st;
  }
}

// ---------------- fused flash attention: 1-tile-ahead REGISTER prefetch of K/adj/V ----------------
// R4 base (fence-free, wave-private cols, pipelined scatter, head-affinity swizzle) + explicit
// software pipeline: tile kt+1's K-fragments, adj-vectors and V-fragments are loaded into named
// registers at the TOP of tile kt's compute, so their latency hides under ~850 cycles of
// MFMA/LDS/softmax work. Loop fully unrolled -> rotation is compile-time register renaming.
__global__ __launch_bounds__(256) void attn_kernel(
    const unsigned short* __restrict__ Qb, const unsigned short* __restrict__ Kb,
    const unsigned short* __restrict__ Vt, const float* __restrict__ adj,
    const float* __restrict__ ea, const int* __restrict__ cnt, const unsigned int* __restrict__ pck,
    const float* __restrict__ shifts, const float* __restrict__ widths,
    const float* __restrict__ selfW, float* __restrict__ out)
{
  __shared__ float S[4][16][68];          // wave-private 16x64 (+4 pad)
  __shared__ float mfin[4][16], lfin[4][16];

  int bid = blockIdx.x;
  // head-affinity XCD swizzle (bijective): XCD = bid&7; h fastest in time within an XCD
  int t8 = bid >> 3;
  int h = t8 & 7;
  int bqt = (bid & 7) * 32 + (t8 >> 3);   // 0..255
  int qt = bqt & 127, b = bqt >> 7;
  int qbase = qt * 16;
  int tid = threadIdx.x, wave = tid >> 6, lane = tid & 63, m = lane & 15, quad = lane >> 4;
  float shift_h = shifts[h];
  float w_h = widths[h];
  float i2w_h = LOG2E / (2.f * w_h * w_h);
  float selfW_h = selfW[h] * LOG2E;
  size_t krow = (size_t)(b * H_ + h) * N_;
  size_t vrow = (size_t)(b * H_ + h) * DH_;
  bf16x8 qfrag = *(const bf16x8*)(Qb + (krow + qbase + m) * DH_ + quad * 8);
  float (*Sw)[68] = S[wave];
  int wcol = wave * 64;

  int rr = lane >> 2, sl0 = lane & 3;     // scatter: 4 lanes per row
  const int* cntp = cnt + ((size_t)(b * N_) + qbase + rr) * 8;
  const unsigned int* pckp = pck + ((size_t)((b * N_ + qbase + rr) * 8)) * ECAP;
  const float* eabase = ea + (size_t)b * E_ * H_ + h;
  const float* adjp = adj + ((size_t)b * N_ + qbase + m) * N_ + wcol + quad * 8;
  const unsigned short* vp0 = Vt + (vrow + m) * N_ + wcol + quad * 8;
  const unsigned short* vp1 = Vt + (vrow + 16 + m) * N_ + wcol + quad * 8;
  const unsigned short* kp  = Kb + (krow + wcol + m) * DH_ + quad * 8;

  floatx4 sh4 = {shift_h, shift_h, shift_h, shift_h};
  floatx4 ni4 = {-i2w_h, -i2w_h, -i2w_h, -i2w_h};
  floatx4 lm4 = {LOG2MIN, LOG2MIN, LOG2MIN, LOG2MIN};

  float mcur = -1e30f, lcur = 0.f;        // wave-local running max / sum for row m
  floatx4 oacc0 = {0.f, 0.f, 0.f, 0.f};
  floatx4 oacc1 = {0.f, 0.f, 0.f, 0.f};

  // ---- operand pipeline prologue (tile 0): K / adj / V into registers ----
  bf16x8 kf_c0 = *(const bf16x8*)(kp);
  bf16x8 kf_c1 = *(const bf16x8*)(kp + (size_t)16 * DH_);
  bf16x8 kf_c2 = *(const bf16x8*)(kp + (size_t)32 * DH_);
  bf16x8 kf_c3 = *(const bf16x8*)(kp + (size_t)48 * DH_);
  floatx4 a_c00 = *(const floatx4*)(adjp);
  floatx4 a_c01 = *(const floatx4*)(adjp + 4);
  floatx4 a_c10 = *(const floatx4*)(adjp + 32);
  floatx4 a_c11 = *(const floatx4*)(adjp + 36);
  bf16x8 vf_c00 = *(const bf16x8*)(vp0);
  bf16x8 vf_c01 = *(const bf16x8*)(vp1);
  bf16x8 vf_c10 = *(const bf16x8*)(vp0 + 32);
  bf16x8 vf_c11 = *(const bf16x8*)(vp1 + 32);

  // ---- scatter pipeline prologue (tile 0): cnt -> pck -> guarded ea ----
  int nb_c = cntp[0]; nb_c = nb_c > ECAP ? ECAP : nb_c;
  unsigned int pk0 = pckp[sl0];
  unsigned int pk1 = pckp[sl0 + 4];
  int c0_c = (int)(pk0 & (N_ - 1)) - wcol;
  int c1_c = (int)(pk1 & (N_ - 1)) - wcol;
  bool g0_c = (sl0 < nb_c) && ((unsigned)c0_c < 64u);
  bool g1_c = (sl0 + 4 < nb_c) && ((unsigned)c1_c < 64u);
  float ea0_c = 0.f, ea1_c = 0.f;
  if (g0_c) ea0_c = eabase[(size_t)(pk0 >> 11) * H_];
  if (g1_c) ea1_c = eabase[(size_t)(pk1 >> 11) * H_];

#pragma unroll
  for (int kt = 0; kt < NKT; ++kt){
    int k0 = kt * KT;
    int k1 = (kt + 1 < NKT) ? k0 + KT : k0;   // clamped: loads unconditional, values unused at tail
    // ---- prefetch NEXT tile's K / adj / V into the _n register set (issue first) ----
    bf16x8 kf_n0 = *(const bf16x8*)(kp + (size_t)(k1)      * DH_);
    bf16x8 kf_n1 = *(const bf16x8*)(kp + (size_t)(k1 + 16) * DH_);
    bf16x8 kf_n2 = *(const bf16x8*)(kp + (size_t)(k1 + 32) * DH_);
    bf16x8 kf_n3 = *(const bf16x8*)(kp + (size_t)(k1 + 48) * DH_);
    const float* apn = adjp + k1;
    floatx4 a_n00 = *(const floatx4*)(apn);
    floatx4 a_n01 = *(const floatx4*)(apn + 4);
    floatx4 a_n10 = *(const floatx4*)(apn + 32);
    floatx4 a_n11 = *(const floatx4*)(apn + 36);
    bf16x8 vf_n00 = *(const bf16x8*)(vp0 + k1);
    bf16x8 vf_n01 = *(const bf16x8*)(vp1 + k1);
    bf16x8 vf_n10 = *(const bf16x8*)(vp0 + k1 + 32);
    bf16x8 vf_n11 = *(const bf16x8*)(vp1 + k1 + 32);
    // ---- prefetch next-tile scatter metadata ----
    int nb_n = 0; unsigned int pk0_n = 0, pk1_n = 0;
    if (kt + 1 < NKT){
      nb_n  = cntp[kt + 1];
      pk0_n = pckp[(kt + 1) * ECAP + sl0];
      pk1_n = pckp[(kt + 1) * ECAP + sl0 + 4];
    }

    // ---- QK^T: this wave's 64 cols x 16 rows (current-tile K regs) ----
    __builtin_amdgcn_s_setprio(1);
    {
      floatx4 acc0 = {0.f, 0.f, 0.f, 0.f};
      acc0 = __builtin_amdgcn_mfma_f32_16x16x32_bf16(qfrag, kf_c0, acc0, 0, 0, 0);
#pragma unroll
      for (int r = 0; r < 4; ++r) Sw[quad * 4 + r][m] = acc0[r];
      floatx4 acc1 = {0.f, 0.f, 0.f, 0.f};
      acc1 = __builtin_amdgcn_mfma_f32_16x16x32_bf16(qfrag, kf_c1, acc1, 0, 0, 0);
#pragma unroll
      for (int r = 0; r < 4; ++r) Sw[quad * 4 + r][16 + m] = acc1[r];
      floatx4 acc2 = {0.f, 0.f, 0.f, 0.f};
      acc2 = __builtin_amdgcn_mfma_f32_16x16x32_bf16(qfrag, kf_c2, acc2, 0, 0, 0);
#pragma unroll
      for (int r = 0; r < 4; ++r) Sw[quad * 4 + r][32 + m] = acc2[r];
      floatx4 acc3 = {0.f, 0.f, 0.f, 0.f};
      acc3 = __builtin_amdgcn_mfma_f32_16x16x32_bf16(qfrag, kf_c3, acc3, 0, 0, 0);
#pragma unroll
      for (int r = 0; r < 4; ++r) Sw[quad * 4 + r][48 + m] = acc3[r];
    }
    __builtin_amdgcn_s_setprio(0);
    // ---- diagonal self-loop fixup (only the owning wave, only the diagonal tile) ----
    {
      int dw = qbase - k0 - wcol;
      if ((unsigned)dw < 64u && lane < 16)
        Sw[lane][dw + lane] += selfW_h;
    }
    // ---- scatter apply (ea values preloaded one tile ago) ----
    if (g0_c) Sw[rr][c0_c] += ea0_c;
    if (g1_c) Sw[rr][c1_c] += ea1_c;
    if (nb_c > 8){                          // rare overflow path (Poisson tail)
      for (int slot = sl0 + 8; slot < nb_c; slot += 4){
        unsigned int p = pckp[kt * ECAP + slot];
        int vv = (int)(p & (N_ - 1));
        int c = vv - k0 - wcol;
        if ((unsigned)c < 64u) Sw[rr][c] += eabase[(size_t)(p >> 11) * H_];
      }
    }
    // ---- issue guarded ea loads for next tile (hide under S-read/moire/softmax) ----
    int c0_n = 0, c1_n = 0; bool g0_n = false, g1_n = false;
    float ea0_n = 0.f, ea1_n = 0.f;
    if (kt + 1 < NKT){
      nb_n = nb_n > ECAP ? ECAP : nb_n;
      c0_n = (int)(pk0_n & (N_ - 1)) - (k0 + KT) - wcol;
      c1_n = (int)(pk1_n & (N_ - 1)) - (k0 + KT) - wcol;
      g0_n = (sl0 < nb_n) && ((unsigned)c0_n < 64u);
      g1_n = (sl0 + 4 < nb_n) && ((unsigned)c1_n < 64u);
      if (g0_n) ea0_n = eabase[(size_t)(pk0_n >> 11) * H_];
      if (g1_n) ea1_n = eabase[(size_t)(pk1_n >> 11) * H_];
    }

    // ---- S rows to regs; moire in packed-f32 registers (current-tile adj regs) ----
    const float* sp = &Sw[m][quad * 8];
    floatx4 s00 = *(const floatx4*)(sp);
    floatx4 s01 = *(const floatx4*)(sp + 4);
    floatx4 s10 = *(const floatx4*)(sp + 32);
    floatx4 s11 = *(const floatx4*)(sp + 36);
    floatx4 d;
    d = a_c00 - sh4; s00 += __builtin_elementwise_max(d * d * ni4, lm4);
    d = a_c01 - sh4; s01 += __builtin_elementwise_max(d * d * ni4, lm4);
    d = a_c10 - sh4; s10 += __builtin_elementwise_max(d * d * ni4, lm4);
    d = a_c11 - sh4; s11 += __builtin_elementwise_max(d * d * ni4, lm4);
    // ---- wave-local row max ----
    float lm = fmaxf(fmaxf(fmaxf(s00.x, s00.y), fmaxf(s00.z, s00.w)),
                     fmaxf(fmaxf(s01.x, s01.y), fmaxf(s01.z, s01.w)));
    lm = fmaxf(lm, fmaxf(fmaxf(fmaxf(s10.x, s10.y), fmaxf(s10.z, s10.w)),
                         fmaxf(fmaxf(s11.x, s11.y), fmaxf(s11.z, s11.w))));
    lm = fmaxf(lm, __shfl_xor(lm, 16));
    lm = fmaxf(lm, __shfl_xor(lm, 32));
    float mnew = fmaxf(mcur, lm);
    float al = fexp2(mcur - mnew);
    mcur = mnew;
    float al0 = __shfl(al, quad * 4 + 0);
    float al1 = __shfl(al, quad * 4 + 1);
    float al2 = __shfl(al, quad * 4 + 2);
    float al3 = __shfl(al, quad * 4 + 3);
    oacc0[0] *= al0; oacc0[1] *= al1; oacc0[2] *= al2; oacc0[3] *= al3;
    oacc1[0] *= al0; oacc1[1] *= al1; oacc1[2] *= al2; oacc1[3] *= al3;
    // ---- P = exp2(S - m), cvt_pk pack, PV MFMA (current-tile V regs), row-sum ----
    floatx4 m4 = {mcur, mcur, mcur, mcur};
    floatx4 e0v = s00 - m4, e1v = s01 - m4, e2v = s10 - m4, e3v = s11 - m4;
    float ps = 0.f, p0, p1;
    union { bf16x8 v; unsigned int u[4]; } P;
    p0 = fexp2(e0v.x); p1 = fexp2(e0v.y); ps += p0 + p1; P.u[0] = cvt_pk_bf16(p0, p1);
    p0 = fexp2(e0v.z); p1 = fexp2(e0v.w); ps += p0 + p1; P.u[1] = cvt_pk_bf16(p0, p1);
    p0 = fexp2(e1v.x); p1 = fexp2(e1v.y); ps += p0 + p1; P.u[2] = cvt_pk_bf16(p0, p1);
    p0 = fexp2(e1v.z); p1 = fexp2(e1v.w); ps += p0 + p1; P.u[3] = cvt_pk_bf16(p0, p1);
    __builtin_amdgcn_s_setprio(1);
    oacc0 = __builtin_amdgcn_mfma_f32_16x16x32_bf16(P.v, vf_c00, oacc0, 0, 0, 0);
    oacc1 = __builtin_amdgcn_mfma_f32_16x16x32_bf16(P.v, vf_c01, oacc1, 0, 0, 0);
    __builtin_amdgcn_s_setprio(0);
    p0 = fexp2(e2v.x); p1 = fexp2(e2v.y); ps += p0 + p1; P.u[0] = cvt_pk_bf16(p0, p1);
    p0 = fexp2(e2v.z); p1 = fexp2(e2v.w); ps += p0 + p1; P.u[1] = cvt_pk_bf16(p0, p1);
    p0 = fexp2(e3v.x); p1 = fexp2(e3v.y); ps += p0 + p1; P.u[2] = cvt_pk_bf16(p0, p1);
    p0 = fexp2(e3v.z); p1 = fexp2(e3v.w); ps += p0 + p1; P.u[3] = cvt_pk_bf16(p0, p1);
    __builtin_amdgcn_s_setprio(1);
    oacc0 = __builtin_amdgcn_mfma_f32_16x16x32_bf16(P.v, vf_c10, oacc0, 0, 0, 0);
    oacc1 = __builtin_amdgcn_mfma_f32_16x16x32_bf16(P.v, vf_c11, oacc1, 0, 0, 0);
    __builtin_amdgcn_s_setprio(0);
    ps += __shfl_xor(ps, 16);
    ps += __shfl_xor(ps, 32);
    lcur = lcur * al + ps;
    // ---- rotate operand + scatter pipelines (compile-time renaming; loop is unrolled) ----
    kf_c0 = kf_n0; kf_c1 = kf_n1; kf_c2 = kf_n2; kf_c3 = kf_n3;
    a_c00 = a_n00; a_c01 = a_n01; a_c10 = a_n10; a_c11 = a_n11;
    vf_c00 = vf_n00; vf_c01 = vf_n01; vf_c10 = vf_n10; vf_c11 = vf_n11;
    nb_c = nb_n; g0_c = g0_n; g1_c = g1_n;
    c0_c = c0_n; c1_c = c1_n; ea0_c = ea0_n; ea1_c = ea1_n;
  }

  // ---- single cross-wave merge: O = sum_w exp2(m_w - m_g) O_w ; l likewise ----
  if (quad == 0){ mfin[wave][m] = mcur; lfin[wave][m] = lcur; }
  float* Ow = &S[wave][0][0];             // each wave parks O in its OWN region
#pragma unroll
  for (int r = 0; r < 4; ++r){
    Ow[(quad * 4 + r) * 32 + m]      = oacc0[r];
    Ow[(quad * 4 + r) * 32 + 16 + m] = oacc1[r];
  }
  __syncthreads();
  const float* Sv = &S[0][0][0];
#pragma unroll
  for (int ii = 0; ii < 2; ++ii){
    int i = tid + ii * 256;
    int r = i >> 5, dcol = i & 31;
    float m0 = mfin[0][r], m1 = mfin[1][r], m2 = mfin[2][r], m3 = mfin[3][r];
    float mg = fmaxf(fmaxf(m0, m1), fmaxf(m2, m3));
    float w0 = fexp2(m0 - mg), w1 = fexp2(m1 - mg);
    float w2 = fexp2(m2 - mg), w3 = fexp2(m3 - mg);
    int o_idx = r * 32 + dcol;
    float o = Sv[o_idx] * w0 + Sv[1088 + o_idx] * w1
            + Sv[2176 + o_idx] * w2 + Sv[3264 + o_idx] * w3;
    float l = lfin[0][r] * w0 + lfin[1][r] * w1 + lfin[2][r] * w2 + lfin[3][r] * w3;
    out[((size_t)b * N_ + qbase + r) * (H_ * DH_) + h * DH_ + dcol] = o / l;
  }
}

extern "C" void kernel_launch(void* const* d_in, const int* in_sizes, int n_in,
                              void* d_out, int out_size, void* d_ws, size_t ws_size,
                              hipStream_t stream)
{
  const float* x      = (const float*)d_in[0];
  const float* adj    = (const float*)d_in[1];
  const float* eattr  = (const float*)d_in[2];
  const float* qkvw   = (const float*)d_in[3];
  const float* qkvb   = (const float*)d_in[4];
  const float* ew1    = (const float*)d_in[5];
  const float* eb1    = (const float*)d_in[6];
  const float* ew2    = (const float*)d_in[7];
  const float* eb2    = (const float*)d_in[8];
  const float* shifts = (const float*)d_in[9];
  const float* widths = (const float*)d_in[10];
  const float* selfW  = (const float*)d_in[11];
  const int*   ei     = (const int*)d_in[12];
  float* out = (float*)d_out;

  char* ws = (char*)d_ws;
  unsigned short* Qb  = (unsigned short*)(ws);                        // 2 MB
  unsigned short* Kb  = (unsigned short*)(ws + ((size_t)2 << 20));    // 2 MB
  unsigned short* Vt  = (unsigned short*)(ws + ((size_t)4 << 20));    // 2 MB
  unsigned short* wT  = (unsigned short*)(ws + ((size_t)6 << 20));    // 384 KB
  float*          ea  = (float*)(ws + ((size_t)7 << 20));             // 4 MB
  int*            cnt = (int*)(ws + ((size_t)11 << 20));              // 128 KB
  unsigned int*  pck  = (unsigned int*)(ws + ((size_t)12 << 20));     // 4 MB (total 16 MB)

  hipMemsetAsync(cnt, 0, (size_t)B_ * N_ * 8 * sizeof(int), stream);
  hipLaunchKernelGGL(prep_kernel, dim3(1280), dim3(256), 0, stream,
                     eattr, ew1, eb1, ew2, eb2, ea, ei, cnt, pck, qkvw, wT);
  hipLaunchKernelGGL(qkv_kernel, dim3(256, 12), dim3(256), 0, stream, x, wT, qkvb, Qb, Kb, Vt);
  hipLaunchKernelGGL(attn_kernel, dim3(B_ * H_ * (N_ / 16)), dim3(256), 0, stream,
                     Qb, Kb, Vt, adj, ea, cnt, pck, shifts, widths, selfW, out);
}

// Round 8
// 222.241 us; speedup vs baseline: 1.0766x; 1.0731x over previous
//
#include <hip/hip_runtime.h>

#define B_ 2
#define N_ 2048
#define H_ 8
#define DH_ 32
#define E_ 65536
#define DIN_ 256
#define KT 256
#define NKT (N_ / KT)
#define ECAP 32
#define QSCALE 0.2550348872f           // log2(e)/sqrt(DH)
#define LOG2E 1.4426950408889634f
#define LOG2MIN -19.931568569324174f   // log2(1e-6)

typedef short bf16x8 __attribute__((ext_vector_type(8)));
typedef float floatx4 __attribute__((ext_vector_type(4)));

__device__ __forceinline__ unsigned short f2b(float f){
  union { float f; unsigned int u; } v; v.f = f;
  return (unsigned short)((v.u + 0x7fffu + ((v.u >> 16) & 1u)) >> 16);
}
__device__ __forceinline__ bf16x8 f8_to_bf(const float* p){
  float4 a = *(const float4*)p, b = *(const float4*)(p + 4);
  bf16x8 r;
  r[0] = (short)f2b(a.x); r[1] = (short)f2b(a.y); r[2] = (short)f2b(a.z); r[3] = (short)f2b(a.w);
  r[4] = (short)f2b(b.x); r[5] = (short)f2b(b.y); r[6] = (short)f2b(b.z); r[7] = (short)f2b(b.w);
  return r;
}
__device__ __forceinline__ unsigned int cvt_pk_bf16(float lo, float hi){
  unsigned int r;
  asm("v_cvt_pk_bf16_f32 %0, %1, %2" : "=v"(r) : "v"(lo), "v"(hi));
  return r;
}
__device__ __forceinline__ float fexp2(float x){
  float r;
  asm("v_exp_f32 %0, %1" : "=v"(r) : "v"(x));
  return r;
}

// ---------------- prep: ffn (blocks 0..511) + fill (512..1023) + wT (1024..1279) ----------------
__global__ __launch_bounds__(256) void prep_kernel(
    const float* __restrict__ eattr,
    const float* __restrict__ w1, const float* __restrict__ b1,
    const float* __restrict__ w2, const float* __restrict__ b2,
    float* __restrict__ ea,
    const int* __restrict__ ei, int* __restrict__ cnt, unsigned int* __restrict__ pck,
    const float* __restrict__ w, unsigned short* __restrict__ wT)
{
  int bb = blockIdx.x, tid = threadIdx.x;
  if (bb < 512){
    __shared__ float W1[64], W2[64], Bv1[8], Bv2[8];
    if (tid < 64){ W1[tid] = w1[tid]; W2[tid] = w2[tid]; }
    if (tid < 8){ Bv1[tid] = b1[tid]; Bv2[tid] = b2[tid]; }
    __syncthreads();
    int gid = bb * 256 + tid;                 // b*E + e
    const float* ep = eattr + (size_t)gid * 8;
    float cur[8];
#pragma unroll
    for (int i = 0; i < 8; ++i) cur[i] = ep[i];
#pragma unroll
    for (int pass = 0; pass < 2; ++pass){
      float t[8];
#pragma unroll
      for (int j = 0; j < 8; ++j){
        float s = Bv1[j];
#pragma unroll
        for (int i = 0; i < 8; ++i) s += cur[i] * W1[i * 8 + j];
        t[j] = fmaxf(s, 0.f);
      }
#pragma unroll
      for (int j = 0; j < 8; ++j){
        float s = Bv2[j];
#pragma unroll
        for (int i = 0; i < 8; ++i) s += t[i] * W2[i * 8 + j];
        cur[j] = s;
      }
    }
    float* op = ea + (size_t)gid * 8;
#pragma unroll
    for (int j = 0; j < 8; ++j) op[j] = cur[j] * LOG2E;   // exp2-domain
  } else if (bb < 1024){
    int gid = (bb - 512) * 256 + tid;         // 0..131071
    int b = gid >> 16, e = gid & (E_ - 1);
    int u = ei[(size_t)b * 2 * E_ + e];
    int v = ei[(size_t)b * 2 * E_ + E_ + e];
    int bucket = ((b << 11) + u) * 8 + (v >> 8);
    int slot = atomicAdd(&cnt[bucket], 1);
    if (slot < ECAP) pck[(size_t)bucket * ECAP + slot] = ((unsigned int)e << 11) | (unsigned int)v;
  } else {
    int k = bb - 1024;                        // 0..255
    for (int c = tid; c < 768; c += 256)
      wT[(size_t)c * 256 + k] = f2b(w[(size_t)k * 768 + c]);
  }
}

// ---------------- QKV projection: (4096x256)@(256x768), MFMA; Q pre-scaled by log2e/sqrt(DH) ----------------
__global__ __launch_bounds__(256) void qkv_kernel(
    const float* __restrict__ x, const unsigned short* __restrict__ wT,
    const float* __restrict__ bias,
    unsigned short* __restrict__ Qb, unsigned short* __restrict__ Kb, unsigned short* __restrict__ Vt)
{
  int tid = threadIdx.x;
  int wave = tid >> 6, lane = tid & 63, m = lane & 15, quad = lane >> 4;
  int rowbase = blockIdx.x * 16;
  int colbase = blockIdx.y * 64 + wave * 16;
  floatx4 acc = {0.f, 0.f, 0.f, 0.f};
#pragma unroll
  for (int kb = 0; kb < 8; ++kb){
    bf16x8 af = f8_to_bf(x + (size_t)(rowbase + m) * DIN_ + kb * 32 + quad * 8);
    bf16x8 bf = *(const bf16x8*)(wT + (size_t)(colbase + m) * DIN_ + kb * 32 + quad * 8);
    acc = __builtin_amdgcn_mfma_f32_16x16x32_bf16(af, bf, acc, 0, 0, 0);
  }
  int ccol = colbase + m;
  int which = ccol >> 8, hh = (ccol >> 5) & 7, dh = ccol & 31;
  float bv = bias[ccol];
  int row0 = rowbase + quad * 4;
  int bidx = row0 >> 11, n0 = row0 & (N_ - 1);
  size_t bh = (size_t)(bidx * H_ + hh);
  if (which == 0){
#pragma unroll
    for (int r = 0; r < 4; ++r)
      Qb[(bh * N_ + n0 + r) * DH_ + dh] = f2b((acc[r] + bv) * QSCALE);
  } else if (which == 1){
#pragma unroll
    for (int r = 0; r < 4; ++r)
      Kb[(bh * N_ + n0 + r) * DH_ + dh] = f2b(acc[r] + bv);
  } else {
    ushort4 st;
    st.x = f2b(acc[0] + bv); st.y = f2b(acc[1] + bv);
    st.z = f2b(acc[2] + bv); st.w = f2b(acc[3] + bv);
    *(ushort4*)(Vt + (bh * DH_ + dh) * N_ + n0) = st;
  }
}

// ---------------- fused flash attention: ONE WAVE = one (b, h, 16 q-rows) problem ----------------
// 1024 WGs x 128 threads (2 waves; wave w handles head hp*2+w). Each wave processes the FULL
// 256-col k-tile (4 col-blocks), so the per-tile fixed costs (softmax shuffle chain, online-max
// update, scatter bookkeeping) amortize over 4x the columns. A wave owns complete rows ->
// NO cross-wave merge, NO __syncthreads anywhere. Same-wave DS ops are in-order -> fence-free.
// Online-max numerics identical to the proven R4 path (single softmax per row, better conditioned).
__global__ __launch_bounds__(128) void attn_kernel(
    const unsigned short* __restrict__ Qb, const unsigned short* __restrict__ Kb,
    const unsigned short* __restrict__ Vt, const float* __restrict__ adj,
    const float* __restrict__ ea, const int* __restrict__ cnt, const unsigned int* __restrict__ pck,
    const float* __restrict__ shifts, const float* __restrict__ widths,
    const float* __restrict__ selfW, float* __restrict__ out)
{
  __shared__ float S[2][16][260];         // per-wave 16x256 (+4 pad; stride%32==4 -> 2-way max)

  int bid = blockIdx.x;                   // 0..1023
  // head-affinity XCD swizzle: XCD = bid&7; the 4 WGs (8 heads) of one (b,qt) adjacent in time.
  int xcd = bid & 7, t = bid >> 3;        // t 0..127
  int hp = t & 3;                         // head pair 0..3
  int bqt = xcd * 32 + (t >> 2);          // 0..255
  int b = bqt >> 7, qt = bqt & 127;
  int qbase = qt * 16;
  int tid = threadIdx.x, wave = tid >> 6, lane = tid & 63, m = lane & 15, quad = lane >> 4;
  int h = hp * 2 + wave;
  float shift_h = shifts[h];
  float w_h = widths[h];
  float i2w_h = LOG2E / (2.f * w_h * w_h);
  float selfW_h = selfW[h] * LOG2E;
  size_t krow = (size_t)(b * H_ + h) * N_;
  size_t vrow = (size_t)(b * H_ + h) * DH_;
  bf16x8 qfrag = *(const bf16x8*)(Qb + (krow + qbase + m) * DH_ + quad * 8);
  float (*Sw)[260] = S[wave];

  int rr = lane >> 2, sl0 = lane & 3;     // scatter: 4 lanes per q-row
  const int* cntp = cnt + ((size_t)(b * N_) + qbase + rr) * 8;
  const unsigned int* pckp = pck + ((size_t)((b * N_ + qbase + rr) * 8)) * ECAP;
  const float* eabase = ea + (size_t)b * E_ * H_ + h;
  const float* adjp = adj + ((size_t)b * N_ + qbase + m) * N_ + quad * 8;
  const unsigned short* vp0 = Vt + (vrow + m) * N_ + quad * 8;
  const unsigned short* vp1 = Vt + (vrow + 16 + m) * N_ + quad * 8;
  const unsigned short* kp  = Kb + (krow + m) * DH_ + quad * 8;

  floatx4 sh4 = {shift_h, shift_h, shift_h, shift_h};
  floatx4 ni4 = {-i2w_h, -i2w_h, -i2w_h, -i2w_h};
  floatx4 lm4 = {LOG2MIN, LOG2MIN, LOG2MIN, LOG2MIN};
  floatx4 z4  = {0.f, 0.f, 0.f, 0.f};

  float mcur = -1e30f, lcur = 0.f;        // running max / sum for row m (full 2048-col rows)
  floatx4 oacc0 = z4, oacc1 = z4;         // O[q=quad*4+r][dh=m] and [dh=16+m]

  // ---- scatter pipeline prologue (tile 0): cnt -> pck -> guarded ea ----
  int nb_c = cntp[0]; nb_c = nb_c > ECAP ? ECAP : nb_c;
  unsigned int pk0 = pckp[sl0];
  unsigned int pk1 = pckp[sl0 + 4];
  int vv0_c = (int)(pk0 & (N_ - 1));
  int vv1_c = (int)(pk1 & (N_ - 1));
  bool g0_c = (sl0 < nb_c);
  bool g1_c = (sl0 + 4 < nb_c);
  float ea0_c = 0.f, ea1_c = 0.f;
  if (g0_c) ea0_c = eabase[(size_t)(pk0 >> 11) * H_];
  if (g1_c) ea1_c = eabase[(size_t)(pk1 >> 11) * H_];

  for (int kt = 0; kt < NKT; ++kt){
    int k0 = kt * KT;
    // ---- prefetch next-tile scatter metadata ----
    int nb_n = 0; unsigned int pk0_n = 0, pk1_n = 0;
    if (kt + 1 < NKT){
      nb_n  = cntp[kt + 1];
      pk0_n = pckp[(kt + 1) * ECAP + sl0];
      pk1_n = pckp[(kt + 1) * ECAP + sl0 + 4];
    }
    // ---- QK^T: full 256 cols x 16 rows (4 col-blocks) ----
#pragma unroll
    for (int cb = 0; cb < 4; ++cb){
      const unsigned short* kpb = kp + (size_t)(k0 + cb * 64) * DH_;
#pragma unroll
      for (int s = 0; s < 4; ++s){
        bf16x8 kf = *(const bf16x8*)(kpb + (size_t)(s * 16) * DH_);
        floatx4 acc = __builtin_amdgcn_mfma_f32_16x16x32_bf16(qfrag, kf, z4, 0, 0, 0);
#pragma unroll
        for (int r = 0; r < 4; ++r)
          Sw[quad * 4 + r][cb * 64 + s * 16 + m] = acc[r];
      }
    }
    // ---- diagonal self-loop fixup ----
    {
      int dw = qbase - k0;
      if ((unsigned)dw < 256u && lane < 16)
        Sw[lane][dw + lane] += selfW_h;
    }
    // ---- scatter apply (ea preloaded one tile ago; bucket always lands in this tile) ----
    if (g0_c) Sw[rr][vv0_c - k0] += ea0_c;
    if (g1_c) Sw[rr][vv1_c - k0] += ea1_c;
    if (nb_c > 8){                          // rare overflow (Poisson tail)
      for (int slot = sl0 + 8; slot < nb_c; slot += 4){
        unsigned int p = pckp[kt * ECAP + slot];
        Sw[rr][(int)(p & (N_ - 1)) - k0] += eabase[(size_t)(p >> 11) * H_];
      }
    }
    // ---- issue guarded ea loads for next tile ----
    int vv0_n = 0, vv1_n = 0; bool g0_n = false, g1_n = false;
    float ea0_n = 0.f, ea1_n = 0.f;
    if (kt + 1 < NKT){
      nb_n = nb_n > ECAP ? ECAP : nb_n;
      vv0_n = (int)(pk0_n & (N_ - 1));
      vv1_n = (int)(pk1_n & (N_ - 1));
      g0_n = (sl0 < nb_n);
      g1_n = (sl0 + 4 < nb_n);
      if (g0_n) ea0_n = eabase[(size_t)(pk0_n >> 11) * H_];
      if (g1_n) ea1_n = eabase[(size_t)(pk1_n >> 11) * H_];
    }
    // ---- S rows to regs + moire, all 4 col-blocks (kept live: 64 VGPRs, static idx) ----
    floatx4 sv[4][4];
#pragma unroll
    for (int cb = 0; cb < 4; ++cb){
      const float* sp = &Sw[m][cb * 64 + quad * 8];
      sv[cb][0] = *(const floatx4*)(sp);
      sv[cb][1] = *(const floatx4*)(sp + 4);
      sv[cb][2] = *(const floatx4*)(sp + 32);
      sv[cb][3] = *(const floatx4*)(sp + 36);
      const float* ap = adjp + k0 + cb * 64;
      floatx4 a0 = *(const floatx4*)(ap);
      floatx4 a1 = *(const floatx4*)(ap + 4);
      floatx4 a2 = *(const floatx4*)(ap + 32);
      floatx4 a3 = *(const floatx4*)(ap + 36);
      floatx4 d;
      d = a0 - sh4; sv[cb][0] += __builtin_elementwise_max(d * d * ni4, lm4);
      d = a1 - sh4; sv[cb][1] += __builtin_elementwise_max(d * d * ni4, lm4);
      d = a2 - sh4; sv[cb][2] += __builtin_elementwise_max(d * d * ni4, lm4);
      d = a3 - sh4; sv[cb][3] += __builtin_elementwise_max(d * d * ni4, lm4);
    }
    // ---- row max over all 256 cols (one shuffle chain per tile) ----
    floatx4 mx01 = __builtin_elementwise_max(
        __builtin_elementwise_max(sv[0][0], sv[0][1]),
        __builtin_elementwise_max(sv[0][2], sv[0][3]));
    floatx4 mx23 = __builtin_elementwise_max(
        __builtin_elementwise_max(sv[1][0], sv[1][1]),
        __builtin_elementwise_max(sv[1][2], sv[1][3]));
    floatx4 mx45 = __builtin_elementwise_max(
        __builtin_elementwise_max(sv[2][0], sv[2][1]),
        __builtin_elementwise_max(sv[2][2], sv[2][3]));
    floatx4 mx67 = __builtin_elementwise_max(
        __builtin_elementwise_max(sv[3][0], sv[3][1]),
        __builtin_elementwise_max(sv[3][2], sv[3][3]));
    floatx4 mxv = __builtin_elementwise_max(__builtin_elementwise_max(mx01, mx23),
                                            __builtin_elementwise_max(mx45, mx67));
    float lm = fmaxf(fmaxf(mxv.x, mxv.y), fmaxf(mxv.z, mxv.w));
    lm = fmaxf(lm, __shfl_xor(lm, 16));
    lm = fmaxf(lm, __shfl_xor(lm, 32));
    float mnew = fmaxf(mcur, lm);
    float al = fexp2(mcur - mnew);
    mcur = mnew;
    float al0 = __shfl(al, quad * 4 + 0);
    float al1 = __shfl(al, quad * 4 + 1);
    float al2 = __shfl(al, quad * 4 + 2);
    float al3 = __shfl(al, quad * 4 + 3);
    oacc0[0] *= al0; oacc0[1] *= al1; oacc0[2] *= al2; oacc0[3] *= al3;
    oacc1[0] *= al0; oacc1[1] *= al1; oacc1[2] *= al2; oacc1[3] *= al3;
    // ---- P = exp2(S - m), pack, PV MFMA per col-block; lane-partial row sum ----
    floatx4 m4 = {mcur, mcur, mcur, mcur};
    floatx4 psv = z4;
#pragma unroll
    for (int cb = 0; cb < 4; ++cb){
      const unsigned short* vA = vp0 + k0 + cb * 64;
      const unsigned short* vB = vp1 + k0 + cb * 64;
      bf16x8 vf00 = *(const bf16x8*)(vA);
      bf16x8 vf01 = *(const bf16x8*)(vB);
      bf16x8 vf10 = *(const bf16x8*)(vA + 32);
      bf16x8 vf11 = *(const bf16x8*)(vB + 32);
      floatx4 e0 = sv[cb][0] - m4, e1 = sv[cb][1] - m4;
      floatx4 e2 = sv[cb][2] - m4, e3 = sv[cb][3] - m4;
      floatx4 p0, p1, p2, p3;
      p0.x = fexp2(e0.x); p0.y = fexp2(e0.y); p0.z = fexp2(e0.z); p0.w = fexp2(e0.w);
      p1.x = fexp2(e1.x); p1.y = fexp2(e1.y); p1.z = fexp2(e1.z); p1.w = fexp2(e1.w);
      p2.x = fexp2(e2.x); p2.y = fexp2(e2.y); p2.z = fexp2(e2.z); p2.w = fexp2(e2.w);
      p3.x = fexp2(e3.x); p3.y = fexp2(e3.y); p3.z = fexp2(e3.z); p3.w = fexp2(e3.w);
      psv += (p0 + p1) + (p2 + p3);
      union { bf16x8 v; unsigned int u[4]; } PL, PH;
      PL.u[0] = cvt_pk_bf16(p0.x, p0.y); PL.u[1] = cvt_pk_bf16(p0.z, p0.w);
      PL.u[2] = cvt_pk_bf16(p1.x, p1.y); PL.u[3] = cvt_pk_bf16(p1.z, p1.w);
      PH.u[0] = cvt_pk_bf16(p2.x, p2.y); PH.u[1] = cvt_pk_bf16(p2.z, p2.w);
      PH.u[2] = cvt_pk_bf16(p3.x, p3.y); PH.u[3] = cvt_pk_bf16(p3.z, p3.w);
      oacc0 = __builtin_amdgcn_mfma_f32_16x16x32_bf16(PL.v, vf00, oacc0, 0, 0, 0);
      oacc1 = __builtin_amdgcn_mfma_f32_16x16x32_bf16(PL.v, vf01, oacc1, 0, 0, 0);
      oacc0 = __builtin_amdgcn_mfma_f32_16x16x32_bf16(PH.v, vf10, oacc0, 0, 0, 0);
      oacc1 = __builtin_amdgcn_mfma_f32_16x16x32_bf16(PH.v, vf11, oacc1, 0, 0, 0);
    }
    float ps = (psv.x + psv.y) + (psv.z + psv.w);
    ps += __shfl_xor(ps, 16);
    ps += __shfl_xor(ps, 32);
    lcur = lcur * al + ps;
    // ---- rotate scatter pipeline ----
    nb_c = nb_n; g0_c = g0_n; g1_c = g1_n;
    vv0_c = vv0_n; vv1_c = vv1_n; ea0_c = ea0_n; ea1_c = ea1_n;
  }

  // ---- direct output (wave owns full rows: no merge, no barrier) ----
  float linv0 = 1.f / __shfl(lcur, quad * 4 + 0);
  float linv1 = 1.f / __shfl(lcur, quad * 4 + 1);
  float linv2 = 1.f / __shfl(lcur, quad * 4 + 2);
  float linv3 = 1.f / __shfl(lcur, quad * 4 + 3);
  float* ob = out + ((size_t)b * N_ + qbase + quad * 4) * (H_ * DH_) + h * DH_;
  ob[0 * H_ * DH_ + m]      = oacc0[0] * linv0;
  ob[0 * H_ * DH_ + 16 + m] = oacc1[0] * linv0;
  ob[1 * H_ * DH_ + m]      = oacc0[1] * linv1;
  ob[1 * H_ * DH_ + 16 + m] = oacc1[1] * linv1;
  ob[2 * H_ * DH_ + m]      = oacc0[2] * linv2;
  ob[2 * H_ * DH_ + 16 + m] = oacc1[2] * linv2;
  ob[3 * H_ * DH_ + m]      = oacc0[3] * linv3;
  ob[3 * H_ * DH_ + 16 + m] = oacc1[3] * linv3;
}

extern "C" void kernel_launch(void* const* d_in, const int* in_sizes, int n_in,
                              void* d_out, int out_size, void* d_ws, size_t ws_size,
                              hipStream_t stream)
{
  const float* x      = (const float*)d_in[0];
  const float* adj    = (const float*)d_in[1];
  const float* eattr  = (const float*)d_in[2];
  const float* qkvw   = (const float*)d_in[3];
  const float* qkvb   = (const float*)d_in[4];
  const float* ew1    = (const float*)d_in[5];
  const float* eb1    = (const float*)d_in[6];
  const float* ew2    = (const float*)d_in[7];
  const float* eb2    = (const float*)d_in[8];
  const float* shifts = (const float*)d_in[9];
  const float* widths = (const float*)d_in[10];
  const float* selfW  = (const float*)d_in[11];
  const int*   ei     = (const int*)d_in[12];
  float* out = (float*)d_out;

  char* ws = (char*)d_ws;
  unsigned short* Qb  = (unsigned short*)(ws);                        // 2 MB
  unsigned short* Kb  = (unsigned short*)(ws + ((size_t)2 << 20));    // 2 MB
  unsigned short* Vt  = (unsigned short*)(ws + ((size_t)4 << 20));    // 2 MB
  unsigned short* wT  = (unsigned short*)(ws + ((size_t)6 << 20));    // 384 KB
  float*          ea  = (float*)(ws + ((size_t)7 << 20));             // 4 MB
  int*            cnt = (int*)(ws + ((size_t)11 << 20));              // 128 KB
  unsigned int*  pck  = (unsigned int*)(ws + ((size_t)12 << 20));     // 4 MB (total 16 MB)

  hipMemsetAsync(cnt, 0, (size_t)B_ * N_ * 8 * sizeof(int), stream);
  hipLaunchKernelGGL(prep_kernel, dim3(1280), dim3(256), 0, stream,
                     eattr, ew1, eb1, ew2, eb2, ea, ei, cnt, pck, qkvw, wT);
  hipLaunchKernelGGL(qkv_kernel, dim3(256, 12), dim3(256), 0, stream, x, wT, qkvb, Qb, Kb, Vt);
  hipLaunchKernelGGL(attn_kernel, dim3(B_ * (H_ / 2) * (N_ / 16)), dim3(128), 0, stream,
                     Qb, Kb, Vt, adj, ea, cnt, pck, shifts, widths, selfW, out);
}

// Round 9
// 210.053 us; speedup vs baseline: 1.1391x; 1.0580x over previous
//
#include <hip/hip_runtime.h>

#define B_ 2
#define N_ 2048
#define H_ 8
#define DH_ 32
#define E_ 65536
#define DIN_ 256
#define KT 256
#define NKT (N_ / KT)
#define ECAP 32
#define QSCALE 0.2550348872f           // log2(e)/sqrt(DH)
#define LOG2E 1.4426950408889634f
#define LOG2MIN -19.931568569324174f   // log2(1e-6)

typedef short bf16x8 __attribute__((ext_vector_type(8)));
typedef float floatx4 __attribute__((ext_vector_type(4)));

__device__ __forceinline__ unsigned short f2b(float f){
  union { float f; unsigned int u; } v; v.f = f;
  return (unsigned short)((v.u + 0x7fffu + ((v.u >> 16) & 1u)) >> 16);
}
__device__ __forceinline__ bf16x8 f8_to_bf(const float* p){
  float4 a = *(const float4*)p, b = *(const float4*)(p + 4);
  bf16x8 r;
  r[0] = (short)f2b(a.x); r[1] = (short)f2b(a.y); r[2] = (short)f2b(a.z); r[3] = (short)f2b(a.w);
  r[4] = (short)f2b(b.x); r[5] = (short)f2b(b.y); r[6] = (short)f2b(b.z); r[7] = (short)f2b(b.w);
  return r;
}
__device__ __forceinline__ unsigned int cvt_pk_bf16(float lo, float hi){
  unsigned int r;
  asm("v_cvt_pk_bf16_f32 %0, %1, %2" : "=v"(r) : "v"(lo), "v"(hi));
  return r;
}
__device__ __forceinline__ float fexp2(float x){
  float r;
  asm("v_exp_f32 %0, %1" : "=v"(r) : "v"(x));
  return r;
}

// ---- prep: ffn (0..511) + fill (512..1023) + wT (1024..1279) + x->bf16 (1280..1791) ----
__global__ __launch_bounds__(256) void prep_kernel(
    const float* __restrict__ eattr,
    const float* __restrict__ w1, const float* __restrict__ b1,
    const float* __restrict__ w2, const float* __restrict__ b2,
    float* __restrict__ ea,
    const int* __restrict__ ei, int* __restrict__ cnt, unsigned int* __restrict__ pck,
    const float* __restrict__ w, unsigned short* __restrict__ wT,
    const float* __restrict__ x, unsigned short* __restrict__ xb)
{
  int bb = blockIdx.x, tid = threadIdx.x;
  if (bb < 512){
    __shared__ float W1[64], W2[64], Bv1[8], Bv2[8];
    if (tid < 64){ W1[tid] = w1[tid]; W2[tid] = w2[tid]; }
    if (tid < 8){ Bv1[tid] = b1[tid]; Bv2[tid] = b2[tid]; }
    __syncthreads();
    int gid = bb * 256 + tid;                 // b*E + e
    const float* ep = eattr + (size_t)gid * 8;
    float cur[8];
#pragma unroll
    for (int i = 0; i < 8; ++i) cur[i] = ep[i];
#pragma unroll
    for (int pass = 0; pass < 2; ++pass){
      float t[8];
#pragma unroll
      for (int j = 0; j < 8; ++j){
        float s = Bv1[j];
#pragma unroll
        for (int i = 0; i < 8; ++i) s += cur[i] * W1[i * 8 + j];
        t[j] = fmaxf(s, 0.f);
      }
#pragma unroll
      for (int j = 0; j < 8; ++j){
        float s = Bv2[j];
#pragma unroll
        for (int i = 0; i < 8; ++i) s += t[i] * W2[i * 8 + j];
        cur[j] = s;
      }
    }
    float* op = ea + (size_t)gid * 8;
#pragma unroll
    for (int j = 0; j < 8; ++j) op[j] = cur[j] * LOG2E;   // exp2-domain
  } else if (bb < 1024){
    int gid = (bb - 512) * 256 + tid;         // 0..131071
    int b = gid >> 16, e = gid & (E_ - 1);
    int u = ei[(size_t)b * 2 * E_ + e];
    int v = ei[(size_t)b * 2 * E_ + E_ + e];
    int bucket = ((b << 11) + u) * 8 + (v >> 8);
    int slot = atomicAdd(&cnt[bucket], 1);
    if (slot < ECAP) pck[(size_t)bucket * ECAP + slot] = ((unsigned int)e << 11) | (unsigned int)v;
  } else if (bb < 1280){
    int k = bb - 1024;                        // 0..255
    for (int c = tid; c < 768; c += 256)
      wT[(size_t)c * 256 + k] = f2b(w[(size_t)k * 768 + c]);
  } else {
    int gid = (bb - 1280) * 256 + tid;        // 0..131071; x is 4096*256 = 1048576 = gid*8
    bf16x8 v = f8_to_bf(x + (size_t)gid * 8);
    *(bf16x8*)(xb + (size_t)gid * 8) = v;
  }
}

// ---------------- QKV projection: bf16 A-input (pre-converted), MFMA; Q pre-scaled ----------------
__global__ __launch_bounds__(256) void qkv_kernel(
    const unsigned short* __restrict__ xb, const unsigned short* __restrict__ wT,
    const float* __restrict__ bias,
    unsigned short* __restrict__ Qb, unsigned short* __restrict__ Kb, unsigned short* __restrict__ Vt)
{
  int tid = threadIdx.x;
  int wave = tid >> 6, lane = tid & 63, m = lane & 15, quad = lane >> 4;
  int rowbase = blockIdx.x * 16;
  int colbase = blockIdx.y * 64 + wave * 16;
  floatx4 acc = {0.f, 0.f, 0.f, 0.f};
#pragma unroll
  for (int kb = 0; kb < 8; ++kb){
    bf16x8 af = *(const bf16x8*)(xb + (size_t)(rowbase + m) * DIN_ + kb * 32 + quad * 8);
    bf16x8 bf = *(const bf16x8*)(wT + (size_t)(colbase + m) * DIN_ + kb * 32 + quad * 8);
    acc = __builtin_amdgcn_mfma_f32_16x16x32_bf16(af, bf, acc, 0, 0, 0);
  }
  int ccol = colbase + m;
  int which = ccol >> 8, hh = (ccol >> 5) & 7, dh = ccol & 31;
  float bv = bias[ccol];
  int row0 = rowbase + quad * 4;
  int bidx = row0 >> 11, n0 = row0 & (N_ - 1);
  size_t bh = (size_t)(bidx * H_ + hh);
  if (which == 0){
#pragma unroll
    for (int r = 0; r < 4; ++r)
      Qb[(bh * N_ + n0 + r) * DH_ + dh] = f2b((acc[r] + bv) * QSCALE);
  } else if (which == 1){
#pragma unroll
    for (int r = 0; r < 4; ++r)
      Kb[(bh * N_ + n0 + r) * DH_ + dh] = f2b(acc[r] + bv);
  } else {
    ushort4 st;
    st.x = f2b(acc[0] + bv); st.y = f2b(acc[1] + bv);
    st.z = f2b(acc[2] + bv); st.w = f2b(acc[3] + bv);
    *(ushort4*)(Vt + (bh * DH_ + dh) * N_ + n0) = st;
  }
}

// ---------------- fused flash attention: ONE WAVE = one (b, h, 16 q-rows); unroll-2 ----------------
// R8 structure (full 256-col tiles, no merge, no barriers, fence-free) + #pragma unroll 2 so the
// scheduler can hoist tile kt+1's adj/K/V global loads into tile kt's softmax/PV window.
__global__ __launch_bounds__(128) void attn_kernel(
    const unsigned short* __restrict__ Qb, const unsigned short* __restrict__ Kb,
    const unsigned short* __restrict__ Vt, const float* __restrict__ adj,
    const float* __restrict__ ea, const int* __restrict__ cnt, const unsigned int* __restrict__ pck,
    const float* __restrict__ shifts, const float* __restrict__ widths,
    const float* __restrict__ selfW, float* __restrict__ out)
{
  __shared__ float S[2][16][260];         // per-wave 16x256 (+4 pad)

  int bid = blockIdx.x;                   // 0..1023
  int xcd = bid & 7, t = bid >> 3;        // t 0..127
  int hp = t & 3;                         // head pair 0..3
  int bqt = xcd * 32 + (t >> 2);          // 0..255
  int b = bqt >> 7, qt = bqt & 127;
  int qbase = qt * 16;
  int tid = threadIdx.x, wave = tid >> 6, lane = tid & 63, m = lane & 15, quad = lane >> 4;
  int h = hp * 2 + wave;
  float shift_h = shifts[h];
  float w_h = widths[h];
  float i2w_h = LOG2E / (2.f * w_h * w_h);
  float selfW_h = selfW[h] * LOG2E;
  size_t krow = (size_t)(b * H_ + h) * N_;
  size_t vrow = (size_t)(b * H_ + h) * DH_;
  bf16x8 qfrag = *(const bf16x8*)(Qb + (krow + qbase + m) * DH_ + quad * 8);
  float (*Sw)[260] = S[wave];

  int rr = lane >> 2, sl0 = lane & 3;     // scatter: 4 lanes per q-row
  const int* cntp = cnt + ((size_t)(b * N_) + qbase + rr) * 8;
  const unsigned int* pckp = pck + ((size_t)((b * N_ + qbase + rr) * 8)) * ECAP;
  const float* eabase = ea + (size_t)b * E_ * H_ + h;
  const float* adjp = adj + ((size_t)b * N_ + qbase + m) * N_ + quad * 8;
  const unsigned short* vp0 = Vt + (vrow + m) * N_ + quad * 8;
  const unsigned short* vp1 = Vt + (vrow + 16 + m) * N_ + quad * 8;
  const unsigned short* kp  = Kb + (krow + m) * DH_ + quad * 8;

  floatx4 sh4 = {shift_h, shift_h, shift_h, shift_h};
  floatx4 ni4 = {-i2w_h, -i2w_h, -i2w_h, -i2w_h};
  floatx4 lm4 = {LOG2MIN, LOG2MIN, LOG2MIN, LOG2MIN};
  floatx4 z4  = {0.f, 0.f, 0.f, 0.f};

  float mcur = -1e30f, lcur = 0.f;
  floatx4 oacc0 = z4, oacc1 = z4;

  // ---- scatter pipeline prologue (tile 0) ----
  int nb_c = cntp[0]; nb_c = nb_c > ECAP ? ECAP : nb_c;
  unsigned int pk0 = pckp[sl0];
  unsigned int pk1 = pckp[sl0 + 4];
  int vv0_c = (int)(pk0 & (N_ - 1));
  int vv1_c = (int)(pk1 & (N_ - 1));
  bool g0_c = (sl0 < nb_c);
  bool g1_c = (sl0 + 4 < nb_c);
  float ea0_c = 0.f, ea1_c = 0.f;
  if (g0_c) ea0_c = eabase[(size_t)(pk0 >> 11) * H_];
  if (g1_c) ea1_c = eabase[(size_t)(pk1 >> 11) * H_];

#pragma unroll 2
  for (int kt = 0; kt < NKT; ++kt){
    int k0 = kt * KT;
    // ---- prefetch next-tile scatter metadata ----
    int nb_n = 0; unsigned int pk0_n = 0, pk1_n = 0;
    if (kt + 1 < NKT){
      nb_n  = cntp[kt + 1];
      pk0_n = pckp[(kt + 1) * ECAP + sl0];
      pk1_n = pckp[(kt + 1) * ECAP + sl0 + 4];
    }
    // ---- QK^T: full 256 cols x 16 rows (4 col-blocks) ----
#pragma unroll
    for (int cb = 0; cb < 4; ++cb){
      const unsigned short* kpb = kp + (size_t)(k0 + cb * 64) * DH_;
#pragma unroll
      for (int s = 0; s < 4; ++s){
        bf16x8 kf = *(const bf16x8*)(kpb + (size_t)(s * 16) * DH_);
        floatx4 acc = __builtin_amdgcn_mfma_f32_16x16x32_bf16(qfrag, kf, z4, 0, 0, 0);
#pragma unroll
        for (int r = 0; r < 4; ++r)
          Sw[quad * 4 + r][cb * 64 + s * 16 + m] = acc[r];
      }
    }
    // ---- diagonal self-loop fixup ----
    {
      int dw = qbase - k0;
      if ((unsigned)dw < 256u && lane < 16)
        Sw[lane][dw + lane] += selfW_h;
    }
    // ---- scatter apply (ea preloaded one tile ago) ----
    if (g0_c) Sw[rr][vv0_c - k0] += ea0_c;
    if (g1_c) Sw[rr][vv1_c - k0] += ea1_c;
    if (nb_c > 8){                          // rare overflow (Poisson tail)
      for (int slot = sl0 + 8; slot < nb_c; slot += 4){
        unsigned int p = pckp[kt * ECAP + slot];
        Sw[rr][(int)(p & (N_ - 1)) - k0] += eabase[(size_t)(p >> 11) * H_];
      }
    }
    // ---- issue guarded ea loads for next tile ----
    int vv0_n = 0, vv1_n = 0; bool g0_n = false, g1_n = false;
    float ea0_n = 0.f, ea1_n = 0.f;
    if (kt + 1 < NKT){
      nb_n = nb_n > ECAP ? ECAP : nb_n;
      vv0_n = (int)(pk0_n & (N_ - 1));
      vv1_n = (int)(pk1_n & (N_ - 1));
      g0_n = (sl0 < nb_n);
      g1_n = (sl0 + 4 < nb_n);
      if (g0_n) ea0_n = eabase[(size_t)(pk0_n >> 11) * H_];
      if (g1_n) ea1_n = eabase[(size_t)(pk1_n >> 11) * H_];
    }
    // ---- S rows to regs + moire, all 4 col-blocks ----
    floatx4 sv[4][4];
#pragma unroll
    for (int cb = 0; cb < 4; ++cb){
      const float* sp = &Sw[m][cb * 64 + quad * 8];
      sv[cb][0] = *(const floatx4*)(sp);
      sv[cb][1] = *(const floatx4*)(sp + 4);
      sv[cb][2] = *(const floatx4*)(sp + 32);
      sv[cb][3] = *(const floatx4*)(sp + 36);
      const float* ap = adjp + k0 + cb * 64;
      floatx4 a0 = *(const floatx4*)(ap);
      floatx4 a1 = *(const floatx4*)(ap + 4);
      floatx4 a2 = *(const floatx4*)(ap + 32);
      floatx4 a3 = *(const floatx4*)(ap + 36);
      floatx4 d;
      d = a0 - sh4; sv[cb][0] += __builtin_elementwise_max(d * d * ni4, lm4);
      d = a1 - sh4; sv[cb][1] += __builtin_elementwise_max(d * d * ni4, lm4);
      d = a2 - sh4; sv[cb][2] += __builtin_elementwise_max(d * d * ni4, lm4);
      d = a3 - sh4; sv[cb][3] += __builtin_elementwise_max(d * d * ni4, lm4);
    }
    // ---- row max over all 256 cols (one shuffle chain per tile) ----
    floatx4 mx01 = __builtin_elementwise_max(
        __builtin_elementwise_max(sv[0][0], sv[0][1]),
        __builtin_elementwise_max(sv[0][2], sv[0][3]));
    floatx4 mx23 = __builtin_elementwise_max(
        __builtin_elementwise_max(sv[1][0], sv[1][1]),
        __builtin_elementwise_max(sv[1][2], sv[1][3]));
    floatx4 mx45 = __builtin_elementwise_max(
        __builtin_elementwise_max(sv[2][0], sv[2][1]),
        __builtin_elementwise_max(sv[2][2], sv[2][3]));
    floatx4 mx67 = __builtin_elementwise_max(
        __builtin_elementwise_max(sv[3][0], sv[3][1]),
        __builtin_elementwise_max(sv[3][2], sv[3][3]));
    floatx4 mxv = __builtin_elementwise_max(__builtin_elementwise_max(mx01, mx23),
                                            __builtin_elementwise_max(mx45, mx67));
    float lm = fmaxf(fmaxf(mxv.x, mxv.y), fmaxf(mxv.z, mxv.w));
    lm = fmaxf(lm, __shfl_xor(lm, 16));
    lm = fmaxf(lm, __shfl_xor(lm, 32));
    float mnew = fmaxf(mcur, lm);
    float al = fexp2(mcur - mnew);
    mcur = mnew;
    float al0 = __shfl(al, quad * 4 + 0);
    float al1 = __shfl(al, quad * 4 + 1);
    float al2 = __shfl(al, quad * 4 + 2);
    float al3 = __shfl(al, quad * 4 + 3);
    oacc0[0] *= al0; oacc0[1] *= al1; oacc0[2] *= al2; oacc0[3] *= al3;
    oacc1[0] *= al0; oacc1[1] *= al1; oacc1[2] *= al2; oacc1[3] *= al3;
    // ---- P = exp2(S - m), pack, PV MFMA per col-block; lane-partial row sum ----
    floatx4 m4 = {mcur, mcur, mcur, mcur};
    floatx4 psv = z4;
#pragma unroll
    for (int cb = 0; cb < 4; ++cb){
      const unsigned short* vA = vp0 + k0 + cb * 64;
      const unsigned short* vB = vp1 + k0 + cb * 64;
      bf16x8 vf00 = *(const bf16x8*)(vA);
      bf16x8 vf01 = *(const bf16x8*)(vB);
      bf16x8 vf10 = *(const bf16x8*)(vA + 32);
      bf16x8 vf11 = *(const bf16x8*)(vB + 32);
      floatx4 e0 = sv[cb][0] - m4, e1 = sv[cb][1] - m4;
      floatx4 e2 = sv[cb][2] - m4, e3 = sv[cb][3] - m4;
      floatx4 p0, p1, p2, p3;
      p0.x = fexp2(e0.x); p0.y = fexp2(e0.y); p0.z = fexp2(e0.z); p0.w = fexp2(e0.w);
      p1.x = fexp2(e1.x); p1.y = fexp2(e1.y); p1.z = fexp2(e1.z); p1.w = fexp2(e1.w);
      p2.x = fexp2(e2.x); p2.y = fexp2(e2.y); p2.z = fexp2(e2.z); p2.w = fexp2(e2.w);
      p3.x = fexp2(e3.x); p3.y = fexp2(e3.y); p3.z = fexp2(e3.z); p3.w = fexp2(e3.w);
      psv += (p0 + p1) + (p2 + p3);
      union { bf16x8 v; unsigned int u[4]; } PL, PH;
      PL.u[0] = cvt_pk_bf16(p0.x, p0.y); PL.u[1] = cvt_pk_bf16(p0.z, p0.w);
      PL.u[2] = cvt_pk_bf16(p1.x, p1.y); PL.u[3] = cvt_pk_bf16(p1.z, p1.w);
      PH.u[0] = cvt_pk_bf16(p2.x, p2.y); PH.u[1] = cvt_pk_bf16(p2.z, p2.w);
      PH.u[2] = cvt_pk_bf16(p3.x, p3.y); PH.u[3] = cvt_pk_bf16(p3.z, p3.w);
      oacc0 = __builtin_amdgcn_mfma_f32_16x16x32_bf16(PL.v, vf00, oacc0, 0, 0, 0);
      oacc1 = __builtin_amdgcn_mfma_f32_16x16x32_bf16(PL.v, vf01, oacc1, 0, 0, 0);
      oacc0 = __builtin_amdgcn_mfma_f32_16x16x32_bf16(PH.v, vf10, oacc0, 0, 0, 0);
      oacc1 = __builtin_amdgcn_mfma_f32_16x16x32_bf16(PH.v, vf11, oacc1, 0, 0, 0);
    }
    float ps = (psv.x + psv.y) + (psv.z + psv.w);
    ps += __shfl_xor(ps, 16);
    ps += __shfl_xor(ps, 32);
    lcur = lcur * al + ps;
    // ---- rotate scatter pipeline ----
    nb_c = nb_n; g0_c = g0_n; g1_c = g1_n;
    vv0_c = vv0_n; vv1_c = vv1_n; ea0_c = ea0_n; ea1_c = ea1_n;
  }

  // ---- direct output (wave owns full rows: no merge, no barrier) ----
  float linv0 = 1.f / __shfl(lcur, quad * 4 + 0);
  float linv1 = 1.f / __shfl(lcur, quad * 4 + 1);
  float linv2 = 1.f / __shfl(lcur, quad * 4 + 2);
  float linv3 = 1.f / __shfl(lcur, quad * 4 + 3);
  float* ob = out + ((size_t)b * N_ + qbase + quad * 4) * (H_ * DH_) + h * DH_;
  ob[0 * H_ * DH_ + m]      = oacc0[0] * linv0;
  ob[0 * H_ * DH_ + 16 + m] = oacc1[0] * linv0;
  ob[1 * H_ * DH_ + m]      = oacc0[1] * linv1;
  ob[1 * H_ * DH_ + 16 + m] = oacc1[1] * linv1;
  ob[2 * H_ * DH_ + m]      = oacc0[2] * linv2;
  ob[2 * H_ * DH_ + 16 + m] = oacc1[2] * linv2;
  ob[3 * H_ * DH_ + m]      = oacc0[3] * linv3;
  ob[3 * H_ * DH_ + 16 + m] = oacc1[3] * linv3;
}

extern "C" void kernel_launch(void* const* d_in, const int* in_sizes, int n_in,
                              void* d_out, int out_size, void* d_ws, size_t ws_size,
                              hipStream_t stream)
{
  const float* x      = (const float*)d_in[0];
  const float* adj    = (const float*)d_in[1];
  const float* eattr  = (const float*)d_in[2];
  const float* qkvw   = (const float*)d_in[3];
  const float* qkvb   = (const float*)d_in[4];
  const float* ew1    = (const float*)d_in[5];
  const float* eb1    = (const float*)d_in[6];
  const float* ew2    = (const float*)d_in[7];
  const float* eb2    = (const float*)d_in[8];
  const float* shifts = (const float*)d_in[9];
  const float* widths = (const float*)d_in[10];
  const float* selfW  = (const float*)d_in[11];
  const int*   ei     = (const int*)d_in[12];
  float* out = (float*)d_out;

  char* ws = (char*)d_ws;
  unsigned short* Qb  = (unsigned short*)(ws);                        // 2 MB
  unsigned short* Kb  = (unsigned short*)(ws + ((size_t)2 << 20));    // 2 MB
  unsigned short* Vt  = (unsigned short*)(ws + ((size_t)4 << 20));    // 2 MB
  unsigned short* wT  = (unsigned short*)(ws + ((size_t)6 << 20));    // 384 KB
  float*          ea  = (float*)(ws + ((size_t)7 << 20));             // 4 MB
  int*            cnt = (int*)(ws + ((size_t)11 << 20));              // 128 KB
  unsigned int*  pck  = (unsigned int*)(ws + ((size_t)12 << 20));     // 4 MB
  unsigned short* xb  = (unsigned short*)(ws + ((size_t)16 << 20));   // 2 MB (total 18 MB)

  hipMemsetAsync(cnt, 0, (size_t)B_ * N_ * 8 * sizeof(int), stream);
  hipLaunchKernelGGL(prep_kernel, dim3(1792), dim3(256), 0, stream,
                     eattr, ew1, eb1, ew2, eb2, ea, ei, cnt, pck, qkvw, wT, x, xb);
  hipLaunchKernelGGL(qkv_kernel, dim3(256, 12), dim3(256), 0, stream, xb, wT, qkvb, Qb, Kb, Vt);
  hipLaunchKernelGGL(attn_kernel, dim3(B_ * (H_ / 2) * (N_ / 16)), dim3(128), 0, stream,
                     Qb, Kb, Vt, adj, ea, cnt, pck, shifts, widths, selfW, out);
}